// Round 3
// baseline (944.515 us; speedup 1.0000x reference)
//
#include <hip/hip_runtime.h>
#include <hip/hip_bf16.h>
#include <math.h>

// TransformerXL forward. bf16-MFMA GEMMs (BK=64, swizzled) + swapped-operand
// flash rel-attention, split-K over key-tiles (3 chunks, grid 1536 = 2 perfect
// rounds at 3 blocks/CU): S^T = mfma(K,Q), P lane-local, in-register pack via
// v_cvt_pk_bf16_f32 + permlane{32,16}_swap; no-max softmax => chunk partials
// (O, li) combine by pure atomic f32 addition; normalize kernel emits bf16.
// Layout: [t,b,*] flattened, m = t*B_ + b.

#define T_   2048
#define B_   2
#define DM   512
#define NH   8
#define DH   64
#define DI   2048
#define INCH 2048
#define NCLS 64
#define MT   4096   // T_*B_

typedef __attribute__((ext_vector_type(8))) short short8;
typedef __attribute__((ext_vector_type(4))) float float4v;

#define QSCALE 0.1803368801111204f   // 0.125 * log2(e)

__device__ inline ushort f2bf(float f) {
  uint u = __float_as_uint(f);
  return (ushort)((u + 0x7FFFu + ((u >> 16) & 1u)) >> 16);   // RNE
}
__device__ inline float bf2f(ushort h) { return __uint_as_float(((uint)h) << 16); }
__device__ inline uint pkbf(float a, float b) {
  __hip_bfloat162 h = __float22bfloat162_rn(float2{a, b});
  return *(uint*)&h;
}
__device__ inline void gload16(const void* g, void* lds) {
  __builtin_amdgcn_global_load_lds(
      (const __attribute__((address_space(1))) void*)g,
      (__attribute__((address_space(3))) void*)lds, 16, 0, 0);
}

// ---------------------------------------------------------------- pos emb (bf16 out)
__global__ __launch_bounds__(256) void pos_kernel(ushort* __restrict__ pe) {
  int idx = blockIdx.x * 256 + threadIdx.x;
  if (idx >= T_ * DM) return;
  int t = idx >> 9;
  int i = idx & 511;
  int j = (i < 256) ? i : (i - 256);
  double invf = exp(-(double)(2 * j) * (9.210340371976184 / 512.0));
  double a = (double)(T_ - 1 - t) * invf;
  pe[idx] = f2bf((i < 256) ? (float)sin(a) : (float)cos(a));
}

// ---------------------------------------------------------------- fused fp32->bf16 (6 segments)
__global__ __launch_bounds__(256) void cvt6_kernel(
    const float* s0, ushort* d0, int n0,
    const float* s1, ushort* d1, int n1,
    const float* s2, ushort* d2, int n2,
    const float* s3, ushort* d3, int n3,
    const float* s4, ushort* d4, int n4,
    const float* s5, ushort* d5, int n5)
{
  const float* s; ushort* d; int n;
  switch (blockIdx.y) {
    case 0: s = s0; d = d0; n = n0; break;
    case 1: s = s1; d = d1; n = n1; break;
    case 2: s = s2; d = d2; n = n2; break;
    case 3: s = s3; d = d3; n = n3; break;
    case 4: s = s4; d = d4; n = n4; break;
    default: s = s5; d = d5; n = n5; break;
  }
  int i = blockIdx.x * 256 + threadIdx.x;
  if (i >= n) return;
  float4 v = ((const float4*)s)[i];
  ushort4 w = { f2bf(v.x), f2bf(v.y), f2bf(v.z), f2bf(v.w) };
  ((ushort4*)d)[i] = w;
}

// ---------------------------------------------------------------- x[B,C,T] -> xb[(t*2+b), C] bf16
__global__ __launch_bounds__(256) void xpose_kernel(const float* __restrict__ x,
                                                    ushort* __restrict__ xb) {
  __shared__ float s[32][33];
  int t0 = blockIdx.x * 32, k0 = blockIdx.y * 32, b = blockIdx.z;
  int tx = threadIdx.x & 31, ty = threadIdx.x >> 5;
#pragma unroll
  for (int l = 0; l < 4; ++l) {
    int k = k0 + ty + l * 8;
    s[ty + l * 8][tx] = x[((size_t)b * INCH + k) * T_ + t0 + tx];
  }
  __syncthreads();
#pragma unroll
  for (int l = 0; l < 4; ++l) {
    int t = t0 + ty + l * 8;
    xb[((size_t)(t * 2 + b)) * INCH + k0 + tx] = f2bf(s[tx][ty + l * 8]);
  }
}

// ---------------------------------------------------------------- V transpose per layer
// heads V section (t,b,n,d) -> vtg[((b*8+n)*64+d)][t]
__global__ __launch_bounds__(256) void vtrans_kernel(const ushort* __restrict__ heads,
                                                     ushort* __restrict__ vtg) {
  __shared__ ushort s[64][72];
  const int tid = threadIdx.x;
  int t0 = blockIdx.x * 64;
  int b = blockIdx.y & 1, n = blockIdx.y >> 1;
  for (int e = tid; e < 512; e += 256) {
    int r = e >> 3, c = e & 7;
    *(uint4*)&s[r][c * 8] =
        *(const uint4*)&heads[(size_t)((t0 + r) * 2 + b) * 1536 + 1024 + n * 64 + c * 8];
  }
  __syncthreads();
  for (int e = tid; e < 512; e += 256) {
    int d = e >> 3, c = e & 7;
    ushort tmp[8];
#pragma unroll
    for (int j = 0; j < 8; ++j) tmp[j] = s[c * 8 + j][d];
    *(uint4*)&vtg[((size_t)((b * 8 + n) * 64 + d)) * (size_t)T_ + t0 + c * 8] = *(uint4*)tmp;
  }
}

// ---------------------------------------------------------------- bf16 MFMA GEMM (BK=64)
template<int TM, int OUTMODE, bool RELU>
__global__ __launch_bounds__(256) void gemm_bf16(
    const ushort* __restrict__ A, const ushort* __restrict__ W,
    const float* __restrict__ bias, float* __restrict__ Cf, ushort* __restrict__ Cb,
    int M, int N, int K)
{
  __shared__ __attribute__((aligned(16))) ushort As[TM * 64];
  __shared__ __attribute__((aligned(16))) ushort Bs[128 * 64];
  const int NI = TM / 32;
  const int tid  = threadIdx.x;
  const int wave = tid >> 6, lane = tid & 63;
  const int quad = lane >> 4, lidx = lane & 15;
  const int m0 = blockIdx.y * TM, n0 = blockIdx.x * 128;
  const int r8 = lane >> 3;
  const int cs = ((lane & 7) ^ (r8 & 7)) * 8;

  float4v acc[NI * 4];
#pragma unroll
  for (int i = 0; i < NI * 4; ++i) acc[i] = (float4v){0.f, 0.f, 0.f, 0.f};

  const int wm = (wave >> 1) * (TM / 2), wn = (wave & 1) * 64;

  for (int k0 = 0; k0 < K; k0 += 64) {
    __syncthreads();
#pragma unroll
    for (int g = 0; g < TM / 32; ++g) {
      int r0 = wave * 8 + g * 32;
      gload16(A + (size_t)(m0 + r0 + r8) * K + k0 + cs, &As[r0 * 64]);
    }
#pragma unroll
    for (int g = 0; g < 4; ++g) {
      int r0 = wave * 8 + g * 32;
      gload16(W + (size_t)(n0 + r0 + r8) * K + k0 + cs, &Bs[r0 * 64]);
    }
    __syncthreads();

#pragma unroll
    for (int kb = 0; kb < 2; ++kb) {
      short8 af[NI], bf4[4];
      const int ch = (((kb * 4 + quad) ^ (lidx & 7)) * 8);
#pragma unroll
      for (int i = 0; i < NI; ++i)
        af[i] = *(const short8*)&As[(wm + i * 16 + lidx) * 64 + ch];
#pragma unroll
      for (int j = 0; j < 4; ++j)
        bf4[j] = *(const short8*)&Bs[(wn + j * 16 + lidx) * 64 + ch];
#pragma unroll
      for (int i = 0; i < NI; ++i)
#pragma unroll
        for (int j = 0; j < 4; ++j)
          acc[i * 4 + j] = __builtin_amdgcn_mfma_f32_16x16x32_bf16(af[i], bf4[j], acc[i * 4 + j], 0, 0, 0);
    }
  }

  float bj[4];
#pragma unroll
  for (int j = 0; j < 4; ++j) bj[j] = bias ? bias[n0 + wn + j * 16 + lidx] : 0.f;
#pragma unroll
  for (int i = 0; i < NI; ++i) {
    int rbase = m0 + wm + i * 16 + quad * 4;
#pragma unroll
    for (int j = 0; j < 4; ++j) {
      int col = n0 + wn + j * 16 + lidx;
#pragma unroll
      for (int reg = 0; reg < 4; ++reg) {
        float v = acc[i * 4 + j][reg] + bj[j];
        if (RELU) v = fmaxf(v, 0.f);
        size_t off = (size_t)(rbase + reg) * N + col;
        if (OUTMODE != 1) Cf[off] = v;
        if (OUTMODE != 0) Cb[off] = f2bf(v);
      }
    }
  }
}

// ---------------------------------------------------------------- fp32 GEMM (cls only)
#define BM 128
#define BN 128
#define BK 16
#define LDT 132

__global__ __launch_bounds__(256) void gemm_f32(
    const float* __restrict__ A, const float* __restrict__ W,
    const float* __restrict__ bias, float* __restrict__ C,
    int M, int N, int K)
{
  __shared__ float Asm[BK][LDT];
  __shared__ float Wsm[BK][LDT];
  const int tid = threadIdx.x;
  const int m0 = blockIdx.y * BM;
  const int n0 = blockIdx.x * BN;
  const int row = tid >> 1;
  const int kh  = (tid & 1) * 8;
  const int ty  = tid >> 4;
  const int tx  = tid & 15;

  float acc[8][8];
#pragma unroll
  for (int i = 0; i < 8; ++i)
#pragma unroll
    for (int j = 0; j < 8; ++j) acc[i][j] = 0.f;

  for (int kt = 0; kt < K; kt += BK) {
    float a_reg[8], w_reg[8];
    {
      const float* ap = A + (size_t)(m0 + row) * K + (kt + kh);
      float4 v0 = *(const float4*)ap;
      float4 v1 = *(const float4*)(ap + 4);
      a_reg[0] = v0.x; a_reg[1] = v0.y; a_reg[2] = v0.z; a_reg[3] = v0.w;
      a_reg[4] = v1.x; a_reg[5] = v1.y; a_reg[6] = v1.z; a_reg[7] = v1.w;
    }
    {
      int nn = n0 + row;
      if (nn < N) {
        const float* wp = W + (size_t)nn * K + (kt + kh);
        float4 v0 = *(const float4*)wp;
        float4 v1 = *(const float4*)(wp + 4);
        w_reg[0] = v0.x; w_reg[1] = v0.y; w_reg[2] = v0.z; w_reg[3] = v0.w;
        w_reg[4] = v1.x; w_reg[5] = v1.y; w_reg[6] = v1.z; w_reg[7] = v1.w;
      } else {
#pragma unroll
        for (int q = 0; q < 8; ++q) w_reg[q] = 0.f;
      }
    }
    __syncthreads();
#pragma unroll
    for (int q = 0; q < 8; ++q) { Asm[kh + q][row] = a_reg[q]; Wsm[kh + q][row] = w_reg[q]; }
    __syncthreads();
#pragma unroll
    for (int k = 0; k < BK; ++k) {
      float4 a0 = *(const float4*)&Asm[k][ty * 4];
      float4 a1 = *(const float4*)&Asm[k][ty * 4 + 64];
      float4 b0 = *(const float4*)&Wsm[k][tx * 4];
      float4 b1 = *(const float4*)&Wsm[k][tx * 4 + 64];
      float av[8] = {a0.x, a0.y, a0.z, a0.w, a1.x, a1.y, a1.z, a1.w};
      float bv[8] = {b0.x, b0.y, b0.z, b0.w, b1.x, b1.y, b1.z, b1.w};
#pragma unroll
      for (int i = 0; i < 8; ++i)
#pragma unroll
        for (int j = 0; j < 8; ++j) acc[i][j] += av[i] * bv[j];
    }
  }

#pragma unroll
  for (int ih = 0; ih < 2; ++ih)
#pragma unroll
    for (int i = 0; i < 4; ++i) {
      int m = m0 + ty * 4 + ih * 64 + i;
#pragma unroll
      for (int jh = 0; jh < 2; ++jh) {
        int nn = n0 + tx * 4 + jh * 64;
        if (nn < N) {
          float4 v;
          v.x = acc[ih * 4 + i][jh * 4 + 0] + bias[nn + 0];
          v.y = acc[ih * 4 + i][jh * 4 + 1] + bias[nn + 1];
          v.z = acc[ih * 4 + i][jh * 4 + 2] + bias[nn + 2];
          v.w = acc[ih * 4 + i][jh * 4 + 3] + bias[nn + 3];
          *(float4*)&C[(size_t)m * N + nn] = v;
        }
      }
    }
}

// ---------------------------------------------------------------- MFMA flash rel-attn (swapped, split-K)
// Grid z = 3 key-chunks (jt in {[0,11),[11,22),[22,32)}); grid 1536 -> 2 perfect
// rounds at 3 blocks/CU. Block: 64 q-rows of one (b,n); wave owns q-row strip.
// AC swapped: S^T = mfma(K, Q) -> thread holds S[key][row=lidx] lane-local.
// rel_shift gather from Gbt (G table unchanged). No-max base-2 softmax in regs
// (raw v_exp_f32); P packed via v_cvt_pk_bf16_f32 + permlane{32,16}_swap.
// PV swapped; O/li chunk partials accumulated by atomicAdd (pure sums — no max
// rescale), normalized by attn_norm_kernel.
#define GT 68

__device__ inline short8 bfrag(const char* base, int lidx, int quad, int kb) {
  return *(const short8*)(base + lidx * 128 + ((((kb << 2) + quad) ^ (lidx & 7)) << 4));
}

__global__ __launch_bounds__(256, 3) void attn_mfma_kernel(
    const ushort* __restrict__ heads, const ushort* __restrict__ rk,
    const ushort* __restrict__ vtg,
    const float* __restrict__ rwb, const float* __restrict__ rrb,
    float* __restrict__ Oacc, float* __restrict__ Lg)
{
  __shared__ __attribute__((aligned(16))) ushort Ks[64 * 64];    // swizzled [key][d]
  __shared__ __attribute__((aligned(16))) ushort Vt[64 * 64];    // swizzled [d][key]
  __shared__ __attribute__((aligned(16))) ushort Re[128 * 64];   // swizzled [w][d]
  __shared__ __attribute__((aligned(16))) ushort Gbt[128 * GT];  // [w][grow]

  const int tid  = threadIdx.x;
  const int i0   = blockIdx.x * 64;
  const int b    = blockIdx.y & 1;
  const int n    = blockIdx.y >> 1;
  const int chunk = blockIdx.z;
  const int jt0 = (chunk == 0) ? 0  : (chunk == 1 ? 11 : 22);
  const int jt1 = (chunk == 0) ? 11 : (chunk == 1 ? 22 : 32);
  const int wave = tid >> 6;
  const int lane = tid & 63;
  const int quad = lane >> 4;
  const int lidx = lane & 15;
  const int r8   = lane >> 3;
  const int cs8  = ((lane & 7) ^ (r8 & 7)) * 8;
  const int bn64 = (b * 8 + n) * 64;
  const int rloc = wave * 16 + lidx;   // this thread's q-row within block

  // ---- Q fragments in registers.
  // qw: wave's own 16-row strip (B-operand for swapped AC) — 2 frags.
  // qr4/q4: all row-tiles (A-operand for G, unchanged).
  short8 qw[2], qr4[4][2], q4[2];
  {
    auto qfrag = [&](int row, int kb, const float* bias) -> short8 {
      short8 q;
      if (row < T_) q = *(const short8*)&heads[(size_t)(row * 2 + b) * 1536 + n * 64 + kb * 32 + quad * 8];
      else { for (int t = 0; t < 8; ++t) ((ushort*)&q)[t] = 0; }
      short8 o;
#pragma unroll
      for (int t = 0; t < 8; ++t) {
        float f = (bf2f((ushort)((ushort*)&q)[t]) + bias[n * 64 + kb * 32 + quad * 8 + t]) * QSCALE;
        ((ushort*)&o)[t] = f2bf(f);
      }
      return o;
    };
    qw[0] = qfrag(i0 + rloc, 0, rwb);
    qw[1] = qfrag(i0 + rloc, 1, rwb);
#pragma unroll
    for (int rt = 0; rt < 4; ++rt) {
      int row = i0 + rt * 16 + lidx;
      qr4[rt][0] = qfrag(row, 0, rrb); qr4[rt][1] = qfrag(row, 1, rrb);
    }
    int row4 = i0 + 64 + lidx;
    q4[0] = qfrag(row4, 0, rrb); q4[1] = qfrag(row4, 1, rrb);
  }

  // loop-invariant gather bases: per ktile t, addr of Gbt[w(c0)][rloc]
  int a0[4];
#pragma unroll
  for (int t = 0; t < 4; ++t)
    a0[t] = (t * 16 + quad * 4 + 63 - rloc) * GT + rloc;

  float4v oacc[4];
  float4v liacc = (float4v){0.f, 0.f, 0.f, 0.f};
#pragma unroll
  for (int dt = 0; dt < 4; ++dt) oacc[dt] = (float4v){0.f, 0.f, 0.f, 0.f};
  short8 ones8;
#pragma unroll
  for (int t = 0; t < 8; ++t) ((ushort*)&ones8)[t] = 0x3F80;   // bf16 1.0

  auto stageKRe = [&](int jt) {
    int j0 = jt * 64, qmin = j0 + 1984 - i0;
#pragma unroll
    for (int half = 0; half < 2; ++half) {
      int r0 = 8 * wave + 32 * half;
      gload16(heads + (size_t)((j0 + r0 + r8) * 2 + b) * 1536 + 512 + n * 64 + cs8, &Ks[r0 * 64]);
    }
#pragma unroll
    for (int q4i = 0; q4i < 4; ++q4i) {
      int r0 = 8 * wave + 32 * q4i;
      int qh = qmin + r0 + r8;
      int p  = (qh > T_) ? (qh - T_ - 1) : ((qh == T_) ? 0 : qh);
      gload16(rk + (size_t)p * 2048 + n * 64 + cs8, &Re[r0 * 64]);
    }
  };
  auto stageV = [&](int jt) {
    int j0 = jt * 64;
#pragma unroll
    for (int half = 0; half < 2; ++half) {
      int r0 = 8 * wave + 32 * half;
      gload16(vtg + (size_t)(bn64 + r0 + r8) * (size_t)T_ + j0 + cs8, &Vt[r0 * 64]);
    }
  };
  auto fixup = [&](int jt) {   // zero Rext[T] row (after DMA drained)
    int qmin = jt * 64 + 1984 - i0;
    int Tidx = T_ - qmin;
    if (Tidx >= 0 && Tidx < 128) {
      if (tid < 32) ((uint*)Re)[Tidx * 32 + tid] = 0u;
      __syncthreads();
    }
  };

  stageKRe(jt0);
  stageV(jt0);
  __syncthreads();
  fixup(jt0);

  for (int jt = jt0; jt < jt1; ++jt) {
    const int qmin = jt * 64 + 1984 - i0;
    const int wth  = T_ - qmin;   // sel = (w > wth)

    // ---- AC swapped: sv[t][reg] = S[key t*16+quad*4+reg][row lidx(=rloc)]
    float4v sv[4];
#pragma unroll
    for (int t = 0; t < 4; ++t) {
      const char* KsT = (const char*)Ks + t * 2048;
      short8 kf0 = bfrag(KsT, lidx, quad, 0);
      short8 kf1 = bfrag(KsT, lidx, quad, 1);
      float4v c = {0.f, 0.f, 0.f, 0.f};
      c = __builtin_amdgcn_mfma_f32_16x16x32_bf16(kf0, qw[0], c, 0, 0, 0);
      c = __builtin_amdgcn_mfma_f32_16x16x32_bf16(kf1, qw[1], c, 0, 0, 0);
      sv[t] = c;
    }

    // ---- G: strips {wave, wave+4}; C: col->w, row->grow; aligned uint2 stores
#pragma unroll
    for (int si = 0; si < 2; ++si) {
      const int ws = wave + si * 4;
      const int w0 = ws * 16;
      const char* ReW = (const char*)Re + w0 * 128;
      short8 rb0 = bfrag(ReW, lidx, quad, 0);
      short8 rb1 = bfrag(ReW, lidx, quad, 1);
#pragma unroll
      for (int rt = 0; rt < 4; ++rt) {
        bool need = si == 0 ? (rt >= 3 - wave) : (rt <= 3 - wave);
        if (need) {
          float4v g = {0.f, 0.f, 0.f, 0.f};
          g = __builtin_amdgcn_mfma_f32_16x16x32_bf16(qr4[rt][0], rb0, g, 0, 0, 0);
          g = __builtin_amdgcn_mfma_f32_16x16x32_bf16(qr4[rt][1], rb1, g, 0, 0, 0);
          uint2 st; st.x = pkbf(g[0], g[1]); st.y = pkbf(g[2], g[3]);
          *(uint2*)&Gbt[(w0 + lidx) * GT + rt * 16 + quad * 4] = st;
        }
      }
      if (si == 0 && wth < 63) {   // grow=64 row (for sel at r=63), strips w<64
        float4v g = {0.f, 0.f, 0.f, 0.f};
        g = __builtin_amdgcn_mfma_f32_16x16x32_bf16(q4[0], rb0, g, 0, 0, 0);
        g = __builtin_amdgcn_mfma_f32_16x16x32_bf16(q4[1], rb1, g, 0, 0, 0);
        if (quad == 0) Gbt[(w0 + lidx) * GT + 64] = f2bf(g[0]);
      }
    }
    __syncthreads();   // B1: Gbt ready; Ks/Re consumed; Vt(jt) DMA drained

    if (jt + 1 < jt1) stageKRe(jt + 1);   // DMA overlaps gather; drains at B2

    // ---- gather BD + no-max base-2 softmax, in registers (raw v_exp_f32)
    {
      const int cth = wth + rloc - 63;   // sel = (c > cth)
#pragma unroll
      for (int t = 0; t < 4; ++t) {
        const int c0 = t * 16 + quad * 4;
#pragma unroll
        for (int r = 0; r < 4; ++r) {
          int ga = a0[t] + r * GT + ((c0 + r > cth) ? 1 : 0);
          sv[t][r] = __builtin_amdgcn_exp2f(sv[t][r] + bf2f(Gbt[ga]));
        }
      }
    }

    // ---- V fragments (B-operand: V[key][d], d = dt*16+lidx)
    short8 vb[4][2];
#pragma unroll
    for (int dt = 0; dt < 4; ++dt) {
      const char* VtT = (const char*)Vt + dt * 2048;
      vb[dt][0] = bfrag(VtT, lidx, quad, 0);
      vb[dt][1] = bfrag(VtT, lidx, quad, 1);
    }

    // ---- pack P to bf16 + in-register quad redistribution -> PV A-frags
    // af[kb] elem j = P[row=lidx][key kb*32+quad*8+j]
    short8 af[2];
#pragma unroll
    for (int kb = 0; kb < 2; ++kb) {
      uint mm[4];
#pragma unroll
      for (int i = 0; i < 2; ++i) {
        uint e, o;
        asm("v_cvt_pk_bf16_f32 %0, %1, %2" : "=v"(e) : "v"(sv[2 * kb][2 * i]),     "v"(sv[2 * kb][2 * i + 1]));
        asm("v_cvt_pk_bf16_f32 %0, %1, %2" : "=v"(o) : "v"(sv[2 * kb + 1][2 * i]), "v"(sv[2 * kb + 1][2 * i + 1]));
        // swap e.rows{2,3} <-> o.rows{0,1}: e1[q]=val(t=2kb+(q>>1), q'=q&1),
        //                                   o1[q]=val(t=2kb+(q>>1), q'=(q&1)+2)
        asm("v_permlane32_swap_b32 %0, %1" : "+v"(e), "+v"(o));
        // swap e.rows{1,3} <-> o.rows{0,2}: e2[q]=val(t, q'=2(q&1)) -> m={0,1}
        //                                   o2[q]=val(t, q'=2(q&1)+1) -> m={2,3}
        asm("v_permlane16_swap_b32 %0, %1" : "+v"(e), "+v"(o));
        mm[i] = e; mm[2 + i] = o;
      }
      union { uint u[4]; short8 s; } cv;
      cv.u[0] = mm[0]; cv.u[1] = mm[1]; cv.u[2] = mm[2]; cv.u[3] = mm[3];
      af[kb] = cv.s;
    }

    __syncthreads();   // B2: all LDS consumed; KRe(jt+1) DMA drained

    if (jt + 1 < jt1) {
      stageV(jt + 1);   // DMA overlaps PV + next AC/G; drains at next B1
      fixup(jt + 1);
    }

    // ---- PV + li (pure registers): O[wave's rows][all d]
#pragma unroll
    for (int dt = 0; dt < 4; ++dt) {
      oacc[dt] = __builtin_amdgcn_mfma_f32_16x16x32_bf16(af[0], vb[dt][0], oacc[dt], 0, 0, 0);
      oacc[dt] = __builtin_amdgcn_mfma_f32_16x16x32_bf16(af[1], vb[dt][1], oacc[dt], 0, 0, 0);
    }
    liacc = __builtin_amdgcn_mfma_f32_16x16x32_bf16(af[0], ones8, liacc, 0, 0, 0);
    liacc = __builtin_amdgcn_mfma_f32_16x16x32_bf16(af[1], ones8, liacc, 0, 0, 0);
  }

  // ---- epilogue: atomic-accumulate chunk partials (coalesced 16-lane rows)
  const int rowg0 = (b * 8 + n) * T_ + i0 + wave * 16 + quad * 4;
#pragma unroll
  for (int reg = 0; reg < 4; ++reg) {
    int rowg = rowg0 + reg;
#pragma unroll
    for (int dt = 0; dt < 4; ++dt)
      atomicAdd(&Oacc[(size_t)rowg * 64 + dt * 16 + lidx], oacc[dt][reg]);
    if (lidx == 0) atomicAdd(&Lg[rowg], liacc[reg]);
  }
}

// ---------------------------------------------------------------- zero partials
__global__ __launch_bounds__(256) void zero2_kernel(float4* __restrict__ a, int na,
                                                    float4* __restrict__ b2, int nb) {
  int i = blockIdx.x * 256 + threadIdx.x;
  if (i < na) a[i] = float4{0.f, 0.f, 0.f, 0.f};
  int j = i - na;
  if (j >= 0 && j < nb) b2[j] = float4{0.f, 0.f, 0.f, 0.f};
}

// ---------------------------------------------------------------- normalize O/li -> avec bf16
__global__ __launch_bounds__(256) void attn_norm_kernel(const float* __restrict__ Oacc,
                                                        const float* __restrict__ Lg,
                                                        ushort* __restrict__ avec) {
  int idx = blockIdx.x * 256 + threadIdx.x;   // over [bn][row][d4], 16*2048*16
  int d4  = idx & 15;
  int row = (idx >> 4) & 2047;
  int bn  = idx >> 15;
  float4 v = ((const float4*)Oacc)[idx];
  float inv = 1.0f / Lg[(bn << 11) + row];
  int b = bn >> 3, n = bn & 7;
  ushort4 w = { f2bf(v.x * inv), f2bf(v.y * inv), f2bf(v.z * inv), f2bf(v.w * inv) };
  *(ushort4*)&avec[(size_t)(row * 2 + b) * DM + n * 64 + d4 * 4] = w;
}

// ---------------------------------------------------------------- LN(residual), dual out
__global__ __launch_bounds__(256) void ln_res_kernel(
    float* __restrict__ h, ushort* __restrict__ hb, const float* __restrict__ delta,
    const float* __restrict__ s, const float* __restrict__ bb)
{
  const int m = blockIdx.x;
  const int tid = threadIdx.x;
  float* hp = h + (size_t)m * DM;
  ushort* hbp = hb + (size_t)m * DM;
  const float* dp = delta + (size_t)m * DM;
  float x0 = hp[tid] + dp[tid];
  float x1 = hp[tid + 256] + dp[tid + 256];
  float sum = x0 + x1, sq = x0 * x0 + x1 * x1;
#pragma unroll
  for (int o = 32; o > 0; o >>= 1) { sum += __shfl_down(sum, o); sq += __shfl_down(sq, o); }
  __shared__ float part[8];
  int wv = tid >> 6;
  if ((tid & 63) == 0) { part[wv * 2] = sum; part[wv * 2 + 1] = sq; }
  __syncthreads();
  float ts = part[0] + part[2] + part[4] + part[6];
  float tq = part[1] + part[3] + part[5] + part[7];
  float mu = ts * (1.f / DM);
  float var = tq * (1.f / DM) - mu * mu;
  float rs = rsqrtf(var + 1e-5f);
  float y0 = (x0 - mu) * rs * s[tid]       + bb[tid];
  float y1 = (x1 - mu) * rs * s[tid + 256] + bb[tid + 256];
  hp[tid] = y0;       hbp[tid] = f2bf(y0);
  hp[tid + 256] = y1; hbp[tid + 256] = f2bf(y1);
}

// ---------------------------------------------------------------- classifier reorder
__global__ __launch_bounds__(256) void reorder_kernel(const float* __restrict__ ct,
                                                      float* __restrict__ out) {
  int idx = blockIdx.x * 256 + threadIdx.x;
  if (idx >= B_ * NCLS * T_) return;
  int t  = idx & (T_ - 1);
  int nc = (idx >> 11) & 63;
  int bb = idx >> 17;
  out[idx] = ct[(size_t)(t * B_ + bb) * NCLS + nc];
}

// ---------------------------------------------------------------- launch
extern "C" void kernel_launch(void* const* d_in, const int* in_sizes, int n_in,
                              void* d_out, int out_size, void* d_ws, size_t ws_size,
                              hipStream_t stream)
{
  const float* x     = (const float*)d_in[0];
  const float* emb_w = (const float*)d_in[1];
  const float* emb_b = (const float*)d_in[2];
  const float* rwb   = (const float*)d_in[3];
  const float* rrb   = (const float*)d_in[4];
  const float* qkv_w = (const float*)d_in[5];
  const float* qkv_b = (const float*)d_in[6];
  const float* rproj = (const float*)d_in[7];
  const float* o_w   = (const float*)d_in[8];
  const float* ln1s  = (const float*)d_in[9];
  const float* ln1b  = (const float*)d_in[10];
  const float* ff1w  = (const float*)d_in[11];
  const float* ff1b  = (const float*)d_in[12];
  const float* ff2w  = (const float*)d_in[13];
  const float* ff2b  = (const float*)d_in[14];
  const float* ln2s  = (const float*)d_in[15];
  const float* ln2b  = (const float*)d_in[16];
  const float* clsw  = (const float*)d_in[17];
  const float* clsb  = (const float*)d_in[18];
  float* out = (float*)d_out;

  char* p = (char*)d_ws;
  float*  h       = (float*)p;   p += (size_t)MT * DM * 4;
  float*  tmpf    = (float*)p;   p += (size_t)MT * DM * 4;
  ushort* hb      = (ushort*)p;  p += (size_t)MT * DM * 2;
  ushort* headsb  = (ushort*)p;  p += (size_t)MT * 1536 * 2;
  ushort* peb     = (ushort*)p;  p += (size_t)T_ * DM * 2;
  ushort* rk_all  = (ushort*)p;  p += (size_t)T_ * 2048 * 2;
  ushort* avecb   = (ushort*)p;  p += (size_t)MT * DM * 2;
  ushort* xfb     = (ushort*)p;  p += (size_t)MT * INCH * 2;
  ushort* emb_wb  = (ushort*)p;  p += (size_t)DM * INCH * 2;
  ushort* qkv_wb  = (ushort*)p;  p += (size_t)4 * 1536 * DM * 2;
  ushort* rproj_wb= (ushort*)p;  p += (size_t)4 * DM * DM * 2;
  ushort* o_wb    = (ushort*)p;  p += (size_t)4 * DM * DM * 2;
  ushort* ff1_wb  = (ushort*)p;  p += (size_t)4 * DI * DM * 2;
  ushort* ff2_wb  = (ushort*)p;  p += (size_t)4 * DM * DI * 2;
  float*  Lg      = (float*)p;   p += (size_t)16 * T_ * 4;
  ushort* vtg     = xfb;   // region reused; live only vtrans->attn

  cvt6_kernel<<<dim3(4096, 6), 256, 0, stream>>>(
      emb_w, emb_wb, DM * INCH / 4,
      qkv_w, qkv_wb, 4 * 1536 * DM / 4,
      rproj, rproj_wb, 4 * DM * DM / 4,
      o_w,   o_wb,   4 * DM * DM / 4,
      ff1w,  ff1_wb, 4 * DI * DM / 4,
      ff2w,  ff2_wb, 4 * DM * DI / 4);
  pos_kernel<<<(T_ * DM) / 256, 256, 0, stream>>>(peb);
  xpose_kernel<<<dim3(T_ / 32, INCH / 32, B_), 256, 0, stream>>>(x, xfb);

  gemm_bf16<64, 2, false><<<dim3(DM / 128, MT / 64), 256, 0, stream>>>(
      xfb, emb_wb, emb_b, h, hb, MT, DM, INCH);
  gemm_bf16<128, 1, false><<<dim3(2048 / 128, T_ / 128), 256, 0, stream>>>(
      peb, rproj_wb, nullptr, nullptr, rk_all, T_, 2048, DM);

  const int NO4 = MT * DM / 4;       // tmpf float4 count (524288)
  const int NL4 = 16 * T_ / 4;       // Lg float4 count (8192)

  for (int l = 0; l < 4; ++l) {
    gemm_bf16<128, 1, false><<<dim3(1536 / 128, MT / 128), 256, 0, stream>>>(
        hb, qkv_wb + (size_t)l * 1536 * DM, qkv_b + l * 1536, nullptr, headsb, MT, 1536, DM);
    vtrans_kernel<<<dim3(T_ / 64, B_ * NH), 256, 0, stream>>>(headsb, vtg);
    zero2_kernel<<<(NO4 + NL4 + 255) / 256, 256, 0, stream>>>(
        (float4*)tmpf, NO4, (float4*)Lg, NL4);
    attn_mfma_kernel<<<dim3(T_ / 64, B_ * NH, 3), 256, 0, stream>>>(
        headsb, rk_all + (size_t)l * 512, vtg, rwb, rrb, tmpf, Lg);
    attn_norm_kernel<<<(16 * T_ * 16) / 256, 256, 0, stream>>>(tmpf, Lg, avecb);
    gemm_bf16<32, 0, false><<<dim3(DM / 128, MT / 32), 256, 0, stream>>>(
        avecb, o_wb + (size_t)l * DM * DM, nullptr, tmpf, nullptr, MT, DM, DM);
    ln_res_kernel<<<MT, 256, 0, stream>>>(h, hb, tmpf, ln1s + l * DM, ln1b + l * DM);
    gemm_bf16<128, 1, true><<<dim3(DI / 128, MT / 128), 256, 0, stream>>>(
        hb, ff1_wb + (size_t)l * DI * DM, ff1b + l * DI, nullptr, xfb, MT, DI, DM);
    gemm_bf16<32, 0, false><<<dim3(DM / 128, MT / 32), 256, 0, stream>>>(
        xfb, ff2_wb + (size_t)l * DM * DI, ff2b + l * DM, tmpf, nullptr, MT, DM, DI);
    ln_res_kernel<<<MT, 256, 0, stream>>>(h, hb, tmpf, ln2s + l * DM, ln2b + l * DM);
  }

  gemm_f32<<<dim3(1, MT / BM), 256, 0, stream>>>(h, clsw, clsb, tmpf, MT, NCLS, DM);
  reorder_kernel<<<(B_ * NCLS * T_) / 256, 256, 0, stream>>>(tmpf, out);
}

// Round 4
// 909.752 us; speedup vs baseline: 1.0382x; 1.0382x over previous
//
#include <hip/hip_runtime.h>
#include <hip/hip_bf16.h>
#include <math.h>

// TransformerXL forward. bf16-MFMA GEMMs (BK=64, swizzled) + swapped-operand
// flash rel-attention, split-K over key-tiles (3 chunks, grid 1536 = 2 perfect
// rounds at 3 blocks/CU): S^T = mfma(K,Q), P lane-local, in-register pack via
// v_cvt_pk_bf16_f32 + permlane{32,16}_swap; no-max softmax => chunk partials
// (O, li) written to DISJOINT per-chunk buffers (plain stores, no atomics/zero);
// norm kernel sums 3 partials and emits bf16. BD gather uses uniform
// all-sel/no-sel fast paths (mixed <= 2 iters/block).
// Layout: [t,b,*] flattened, m = t*B_ + b.

#define T_   2048
#define B_   2
#define DM   512
#define NH   8
#define DH   64
#define DI   2048
#define INCH 2048
#define NCLS 64
#define MT   4096   // T_*B_

typedef __attribute__((ext_vector_type(8))) short short8;
typedef __attribute__((ext_vector_type(4))) float float4v;

#define QSCALE 0.1803368801111204f   // 0.125 * log2(e)

__device__ inline ushort f2bf(float f) {
  uint u = __float_as_uint(f);
  return (ushort)((u + 0x7FFFu + ((u >> 16) & 1u)) >> 16);   // RNE
}
__device__ inline float bf2f(ushort h) { return __uint_as_float(((uint)h) << 16); }
__device__ inline uint pkbf(float a, float b) {
  __hip_bfloat162 h = __float22bfloat162_rn(float2{a, b});
  return *(uint*)&h;
}
__device__ inline void gload16(const void* g, void* lds) {
  __builtin_amdgcn_global_load_lds(
      (const __attribute__((address_space(1))) void*)g,
      (__attribute__((address_space(3))) void*)lds, 16, 0, 0);
}

// ---------------------------------------------------------------- pos emb (bf16 out)
__global__ __launch_bounds__(256) void pos_kernel(ushort* __restrict__ pe) {
  int idx = blockIdx.x * 256 + threadIdx.x;
  if (idx >= T_ * DM) return;
  int t = idx >> 9;
  int i = idx & 511;
  int j = (i < 256) ? i : (i - 256);
  double invf = exp(-(double)(2 * j) * (9.210340371976184 / 512.0));
  double a = (double)(T_ - 1 - t) * invf;
  pe[idx] = f2bf((i < 256) ? (float)sin(a) : (float)cos(a));
}

// ---------------------------------------------------------------- fused fp32->bf16 (6 segments)
__global__ __launch_bounds__(256) void cvt6_kernel(
    const float* s0, ushort* d0, int n0,
    const float* s1, ushort* d1, int n1,
    const float* s2, ushort* d2, int n2,
    const float* s3, ushort* d3, int n3,
    const float* s4, ushort* d4, int n4,
    const float* s5, ushort* d5, int n5)
{
  const float* s; ushort* d; int n;
  switch (blockIdx.y) {
    case 0: s = s0; d = d0; n = n0; break;
    case 1: s = s1; d = d1; n = n1; break;
    case 2: s = s2; d = d2; n = n2; break;
    case 3: s = s3; d = d3; n = n3; break;
    case 4: s = s4; d = d4; n = n4; break;
    default: s = s5; d = d5; n = n5; break;
  }
  int i = blockIdx.x * 256 + threadIdx.x;
  if (i >= n) return;
  float4 v = ((const float4*)s)[i];
  ushort4 w = { f2bf(v.x), f2bf(v.y), f2bf(v.z), f2bf(v.w) };
  ((ushort4*)d)[i] = w;
}

// ---------------------------------------------------------------- x[B,C,T] -> xb[(t*2+b), C] bf16
__global__ __launch_bounds__(256) void xpose_kernel(const float* __restrict__ x,
                                                    ushort* __restrict__ xb) {
  __shared__ float s[32][33];
  int t0 = blockIdx.x * 32, k0 = blockIdx.y * 32, b = blockIdx.z;
  int tx = threadIdx.x & 31, ty = threadIdx.x >> 5;
#pragma unroll
  for (int l = 0; l < 4; ++l) {
    int k = k0 + ty + l * 8;
    s[ty + l * 8][tx] = x[((size_t)b * INCH + k) * T_ + t0 + tx];
  }
  __syncthreads();
#pragma unroll
  for (int l = 0; l < 4; ++l) {
    int t = t0 + ty + l * 8;
    xb[((size_t)(t * 2 + b)) * INCH + k0 + tx] = f2bf(s[tx][ty + l * 8]);
  }
}

// ---------------------------------------------------------------- V transpose per layer
// heads V section (t,b,n,d) -> vtg[((b*8+n)*64+d)][t]
__global__ __launch_bounds__(256) void vtrans_kernel(const ushort* __restrict__ heads,
                                                     ushort* __restrict__ vtg) {
  __shared__ ushort s[64][72];
  const int tid = threadIdx.x;
  int t0 = blockIdx.x * 64;
  int b = blockIdx.y & 1, n = blockIdx.y >> 1;
  for (int e = tid; e < 512; e += 256) {
    int r = e >> 3, c = e & 7;
    *(uint4*)&s[r][c * 8] =
        *(const uint4*)&heads[(size_t)((t0 + r) * 2 + b) * 1536 + 1024 + n * 64 + c * 8];
  }
  __syncthreads();
  for (int e = tid; e < 512; e += 256) {
    int d = e >> 3, c = e & 7;
    ushort tmp[8];
#pragma unroll
    for (int j = 0; j < 8; ++j) tmp[j] = s[c * 8 + j][d];
    *(uint4*)&vtg[((size_t)((b * 8 + n) * 64 + d)) * (size_t)T_ + t0 + c * 8] = *(uint4*)tmp;
  }
}

// ---------------------------------------------------------------- bf16 MFMA GEMM (BK=64)
template<int TM, int OUTMODE, bool RELU>
__global__ __launch_bounds__(256) void gemm_bf16(
    const ushort* __restrict__ A, const ushort* __restrict__ W,
    const float* __restrict__ bias, float* __restrict__ Cf, ushort* __restrict__ Cb,
    int M, int N, int K)
{
  __shared__ __attribute__((aligned(16))) ushort As[TM * 64];
  __shared__ __attribute__((aligned(16))) ushort Bs[128 * 64];
  const int NI = TM / 32;
  const int tid  = threadIdx.x;
  const int wave = tid >> 6, lane = tid & 63;
  const int quad = lane >> 4, lidx = lane & 15;
  const int m0 = blockIdx.y * TM, n0 = blockIdx.x * 128;
  const int r8 = lane >> 3;
  const int cs = ((lane & 7) ^ (r8 & 7)) * 8;

  float4v acc[NI * 4];
#pragma unroll
  for (int i = 0; i < NI * 4; ++i) acc[i] = (float4v){0.f, 0.f, 0.f, 0.f};

  const int wm = (wave >> 1) * (TM / 2), wn = (wave & 1) * 64;

  for (int k0 = 0; k0 < K; k0 += 64) {
    __syncthreads();
#pragma unroll
    for (int g = 0; g < TM / 32; ++g) {
      int r0 = wave * 8 + g * 32;
      gload16(A + (size_t)(m0 + r0 + r8) * K + k0 + cs, &As[r0 * 64]);
    }
#pragma unroll
    for (int g = 0; g < 4; ++g) {
      int r0 = wave * 8 + g * 32;
      gload16(W + (size_t)(n0 + r0 + r8) * K + k0 + cs, &Bs[r0 * 64]);
    }
    __syncthreads();

#pragma unroll
    for (int kb = 0; kb < 2; ++kb) {
      short8 af[NI], bf4[4];
      const int ch = (((kb * 4 + quad) ^ (lidx & 7)) * 8);
#pragma unroll
      for (int i = 0; i < NI; ++i)
        af[i] = *(const short8*)&As[(wm + i * 16 + lidx) * 64 + ch];
#pragma unroll
      for (int j = 0; j < 4; ++j)
        bf4[j] = *(const short8*)&Bs[(wn + j * 16 + lidx) * 64 + ch];
#pragma unroll
      for (int i = 0; i < NI; ++i)
#pragma unroll
        for (int j = 0; j < 4; ++j)
          acc[i * 4 + j] = __builtin_amdgcn_mfma_f32_16x16x32_bf16(af[i], bf4[j], acc[i * 4 + j], 0, 0, 0);
    }
  }

  float bj[4];
#pragma unroll
  for (int j = 0; j < 4; ++j) bj[j] = bias ? bias[n0 + wn + j * 16 + lidx] : 0.f;
#pragma unroll
  for (int i = 0; i < NI; ++i) {
    int rbase = m0 + wm + i * 16 + quad * 4;
#pragma unroll
    for (int j = 0; j < 4; ++j) {
      int col = n0 + wn + j * 16 + lidx;
#pragma unroll
      for (int reg = 0; reg < 4; ++reg) {
        float v = acc[i * 4 + j][reg] + bj[j];
        if (RELU) v = fmaxf(v, 0.f);
        size_t off = (size_t)(rbase + reg) * N + col;
        if (OUTMODE != 1) Cf[off] = v;
        if (OUTMODE != 0) Cb[off] = f2bf(v);
      }
    }
  }
}

// ---------------------------------------------------------------- fp32 GEMM (cls only)
#define BM 128
#define BN 128
#define BK 16
#define LDT 132

__global__ __launch_bounds__(256) void gemm_f32(
    const float* __restrict__ A, const float* __restrict__ W,
    const float* __restrict__ bias, float* __restrict__ C,
    int M, int N, int K)
{
  __shared__ float Asm[BK][LDT];
  __shared__ float Wsm[BK][LDT];
  const int tid = threadIdx.x;
  const int m0 = blockIdx.y * BM;
  const int n0 = blockIdx.x * BN;
  const int row = tid >> 1;
  const int kh  = (tid & 1) * 8;
  const int ty  = tid >> 4;
  const int tx  = tid & 15;

  float acc[8][8];
#pragma unroll
  for (int i = 0; i < 8; ++i)
#pragma unroll
    for (int j = 0; j < 8; ++j) acc[i][j] = 0.f;

  for (int kt = 0; kt < K; kt += BK) {
    float a_reg[8], w_reg[8];
    {
      const float* ap = A + (size_t)(m0 + row) * K + (kt + kh);
      float4 v0 = *(const float4*)ap;
      float4 v1 = *(const float4*)(ap + 4);
      a_reg[0] = v0.x; a_reg[1] = v0.y; a_reg[2] = v0.z; a_reg[3] = v0.w;
      a_reg[4] = v1.x; a_reg[5] = v1.y; a_reg[6] = v1.z; a_reg[7] = v1.w;
    }
    {
      int nn = n0 + row;
      if (nn < N) {
        const float* wp = W + (size_t)nn * K + (kt + kh);
        float4 v0 = *(const float4*)wp;
        float4 v1 = *(const float4*)(wp + 4);
        w_reg[0] = v0.x; w_reg[1] = v0.y; w_reg[2] = v0.z; w_reg[3] = v0.w;
        w_reg[4] = v1.x; w_reg[5] = v1.y; w_reg[6] = v1.z; w_reg[7] = v1.w;
      } else {
#pragma unroll
        for (int q = 0; q < 8; ++q) w_reg[q] = 0.f;
      }
    }
    __syncthreads();
#pragma unroll
    for (int q = 0; q < 8; ++q) { Asm[kh + q][row] = a_reg[q]; Wsm[kh + q][row] = w_reg[q]; }
    __syncthreads();
#pragma unroll
    for (int k = 0; k < BK; ++k) {
      float4 a0 = *(const float4*)&Asm[k][ty * 4];
      float4 a1 = *(const float4*)&Asm[k][ty * 4 + 64];
      float4 b0 = *(const float4*)&Wsm[k][tx * 4];
      float4 b1 = *(const float4*)&Wsm[k][tx * 4 + 64];
      float av[8] = {a0.x, a0.y, a0.z, a0.w, a1.x, a1.y, a1.z, a1.w};
      float bv[8] = {b0.x, b0.y, b0.z, b0.w, b1.x, b1.y, b1.z, b1.w};
#pragma unroll
      for (int i = 0; i < 8; ++i)
#pragma unroll
        for (int j = 0; j < 8; ++j) acc[i][j] += av[i] * bv[j];
    }
  }

#pragma unroll
  for (int ih = 0; ih < 2; ++ih)
#pragma unroll
    for (int i = 0; i < 4; ++i) {
      int m = m0 + ty * 4 + ih * 64 + i;
#pragma unroll
      for (int jh = 0; jh < 2; ++jh) {
        int nn = n0 + tx * 4 + jh * 64;
        if (nn < N) {
          float4 v;
          v.x = acc[ih * 4 + i][jh * 4 + 0] + bias[nn + 0];
          v.y = acc[ih * 4 + i][jh * 4 + 1] + bias[nn + 1];
          v.z = acc[ih * 4 + i][jh * 4 + 2] + bias[nn + 2];
          v.w = acc[ih * 4 + i][jh * 4 + 3] + bias[nn + 3];
          *(float4*)&C[(size_t)m * N + nn] = v;
        }
      }
    }
}

// ---------------------------------------------------------------- MFMA flash rel-attn (swapped, split-K)
// Grid z = 3 key-chunks (jt in {[0,11),[11,22),[22,32)}); grid 1536 -> 2 perfect
// rounds at 3 blocks/CU. Block: 64 q-rows of one (b,n); wave owns q-row strip.
// AC swapped: S^T = mfma(K, Q) -> thread holds S[key][row=lidx] lane-local.
// rel_shift gather from Gbt; sel = (w > wth) classified block-uniform:
// all-sel (wth<0) / no-sel (wth>=126) fast paths, per-element only for the
// <=2 mixed iterations. No-max base-2 softmax in regs (raw v_exp_f32);
// P packed via v_cvt_pk_bf16_f32 + permlane{32,16}_swap. PV swapped;
// O/li chunk partials go to disjoint per-chunk buffers (plain stores).
#define GT 68

__device__ inline short8 bfrag(const char* base, int lidx, int quad, int kb) {
  return *(const short8*)(base + lidx * 128 + ((((kb << 2) + quad) ^ (lidx & 7)) << 4));
}

__global__ __launch_bounds__(256, 3) void attn_mfma_kernel(
    const ushort* __restrict__ heads, const ushort* __restrict__ rk,
    const ushort* __restrict__ vtg,
    const float* __restrict__ rwb, const float* __restrict__ rrb,
    float* __restrict__ O0, float* __restrict__ O1, float* __restrict__ O2,
    float* __restrict__ Lp)
{
  __shared__ __attribute__((aligned(16))) ushort Ks[64 * 64];    // swizzled [key][d]
  __shared__ __attribute__((aligned(16))) ushort Vt[64 * 64];    // swizzled [d][key]
  __shared__ __attribute__((aligned(16))) ushort Re[128 * 64];   // swizzled [w][d]
  __shared__ __attribute__((aligned(16))) ushort Gbt[128 * GT];  // [w][grow]

  const int tid  = threadIdx.x;
  const int i0   = blockIdx.x * 64;
  const int b    = blockIdx.y & 1;
  const int n    = blockIdx.y >> 1;
  const int chunk = blockIdx.z;
  const int jt0 = (chunk == 0) ? 0  : (chunk == 1 ? 11 : 22);
  const int jt1 = (chunk == 0) ? 11 : (chunk == 1 ? 22 : 32);
  const int wave = tid >> 6;
  const int lane = tid & 63;
  const int quad = lane >> 4;
  const int lidx = lane & 15;
  const int r8   = lane >> 3;
  const int cs8  = ((lane & 7) ^ (r8 & 7)) * 8;
  const int bn64 = (b * 8 + n) * 64;
  const int rloc = wave * 16 + lidx;   // this thread's q-row within block

  // ---- Q fragments in registers.
  short8 qw[2], qr4[4][2], q4[2];
  {
    auto qfrag = [&](int row, int kb, const float* bias) -> short8 {
      short8 q;
      if (row < T_) q = *(const short8*)&heads[(size_t)(row * 2 + b) * 1536 + n * 64 + kb * 32 + quad * 8];
      else { for (int t = 0; t < 8; ++t) ((ushort*)&q)[t] = 0; }
      short8 o;
#pragma unroll
      for (int t = 0; t < 8; ++t) {
        float f = (bf2f((ushort)((ushort*)&q)[t]) + bias[n * 64 + kb * 32 + quad * 8 + t]) * QSCALE;
        ((ushort*)&o)[t] = f2bf(f);
      }
      return o;
    };
    qw[0] = qfrag(i0 + rloc, 0, rwb);
    qw[1] = qfrag(i0 + rloc, 1, rwb);
#pragma unroll
    for (int rt = 0; rt < 4; ++rt) {
      int row = i0 + rt * 16 + lidx;
      qr4[rt][0] = qfrag(row, 0, rrb); qr4[rt][1] = qfrag(row, 1, rrb);
    }
    int row4 = i0 + 64 + lidx;
    q4[0] = qfrag(row4, 0, rrb); q4[1] = qfrag(row4, 1, rrb);
  }

  // loop-invariant gather bases: per ktile t, addr of Gbt[w(c0)][rloc]
  int a0[4];
#pragma unroll
  for (int t = 0; t < 4; ++t)
    a0[t] = (t * 16 + quad * 4 + 63 - rloc) * GT + rloc;

  float4v oacc[4];
  float4v liacc = (float4v){0.f, 0.f, 0.f, 0.f};
#pragma unroll
  for (int dt = 0; dt < 4; ++dt) oacc[dt] = (float4v){0.f, 0.f, 0.f, 0.f};
  short8 ones8;
#pragma unroll
  for (int t = 0; t < 8; ++t) ((ushort*)&ones8)[t] = 0x3F80;   // bf16 1.0

  auto stageKRe = [&](int jt) {
    int j0 = jt * 64, qmin = j0 + 1984 - i0;
#pragma unroll
    for (int half = 0; half < 2; ++half) {
      int r0 = 8 * wave + 32 * half;
      gload16(heads + (size_t)((j0 + r0 + r8) * 2 + b) * 1536 + 512 + n * 64 + cs8, &Ks[r0 * 64]);
    }
#pragma unroll
    for (int q4i = 0; q4i < 4; ++q4i) {
      int r0 = 8 * wave + 32 * q4i;
      int qh = qmin + r0 + r8;
      int p  = (qh > T_) ? (qh - T_ - 1) : ((qh == T_) ? 0 : qh);
      gload16(rk + (size_t)p * 2048 + n * 64 + cs8, &Re[r0 * 64]);
    }
  };
  auto stageV = [&](int jt) {
    int j0 = jt * 64;
#pragma unroll
    for (int half = 0; half < 2; ++half) {
      int r0 = 8 * wave + 32 * half;
      gload16(vtg + (size_t)(bn64 + r0 + r8) * (size_t)T_ + j0 + cs8, &Vt[r0 * 64]);
    }
  };
  auto fixup = [&](int jt) {   // zero Rext[T] row (after DMA drained)
    int qmin = jt * 64 + 1984 - i0;
    int Tidx = T_ - qmin;
    if (Tidx >= 0 && Tidx < 128) {
      if (tid < 32) ((uint*)Re)[Tidx * 32 + tid] = 0u;
      __syncthreads();
    }
  };

  stageKRe(jt0);
  stageV(jt0);
  __syncthreads();
  fixup(jt0);

  for (int jt = jt0; jt < jt1; ++jt) {
    const int qmin = jt * 64 + 1984 - i0;
    const int wth  = T_ - qmin;   // sel = (w > wth)

    // ---- AC swapped: sv[t][reg] = S[key t*16+quad*4+reg][row lidx(=rloc)]
    float4v sv[4];
#pragma unroll
    for (int t = 0; t < 4; ++t) {
      const char* KsT = (const char*)Ks + t * 2048;
      short8 kf0 = bfrag(KsT, lidx, quad, 0);
      short8 kf1 = bfrag(KsT, lidx, quad, 1);
      float4v c = {0.f, 0.f, 0.f, 0.f};
      c = __builtin_amdgcn_mfma_f32_16x16x32_bf16(kf0, qw[0], c, 0, 0, 0);
      c = __builtin_amdgcn_mfma_f32_16x16x32_bf16(kf1, qw[1], c, 0, 0, 0);
      sv[t] = c;
    }

    // ---- G: strips {wave, wave+4}; C: col->w, row->grow; aligned uint2 stores
#pragma unroll
    for (int si = 0; si < 2; ++si) {
      const int ws = wave + si * 4;
      const int w0 = ws * 16;
      const char* ReW = (const char*)Re + w0 * 128;
      short8 rb0 = bfrag(ReW, lidx, quad, 0);
      short8 rb1 = bfrag(ReW, lidx, quad, 1);
#pragma unroll
      for (int rt = 0; rt < 4; ++rt) {
        bool need = si == 0 ? (rt >= 3 - wave) : (rt <= 3 - wave);
        if (need) {
          float4v g = {0.f, 0.f, 0.f, 0.f};
          g = __builtin_amdgcn_mfma_f32_16x16x32_bf16(qr4[rt][0], rb0, g, 0, 0, 0);
          g = __builtin_amdgcn_mfma_f32_16x16x32_bf16(qr4[rt][1], rb1, g, 0, 0, 0);
          uint2 st; st.x = pkbf(g[0], g[1]); st.y = pkbf(g[2], g[3]);
          *(uint2*)&Gbt[(w0 + lidx) * GT + rt * 16 + quad * 4] = st;
        }
      }
      if (si == 0 && wth < 63) {   // grow=64 row (for sel at r=63), strips w<64
        float4v g = {0.f, 0.f, 0.f, 0.f};
        g = __builtin_amdgcn_mfma_f32_16x16x32_bf16(q4[0], rb0, g, 0, 0, 0);
        g = __builtin_amdgcn_mfma_f32_16x16x32_bf16(q4[1], rb1, g, 0, 0, 0);
        if (quad == 0) Gbt[(w0 + lidx) * GT + 64] = f2bf(g[0]);
      }
    }
    __syncthreads();   // B1: Gbt ready; Ks/Re consumed; Vt(jt) DMA drained

    if (jt + 1 < jt1) stageKRe(jt + 1);   // DMA overlaps gather; drains at B2

    // ---- gather BD + no-max base-2 softmax, in registers (raw v_exp_f32)
    // sel = (c > cth) is block-uniform-classifiable: no-sel iff wth>=126,
    // all-sel iff wth<0; mixed hits <=2 iterations per block.
    if (wth >= 126) {
#pragma unroll
      for (int t = 0; t < 4; ++t)
#pragma unroll
        for (int r = 0; r < 4; ++r)
          sv[t][r] = __builtin_amdgcn_exp2f(sv[t][r] + bf2f(Gbt[a0[t] + r * GT]));
    } else if (wth < 0) {
#pragma unroll
      for (int t = 0; t < 4; ++t)
#pragma unroll
        for (int r = 0; r < 4; ++r)
          sv[t][r] = __builtin_amdgcn_exp2f(sv[t][r] + bf2f(Gbt[a0[t] + r * GT + 1]));
    } else {
      const int cth = wth + rloc - 63;   // sel = (c > cth)
#pragma unroll
      for (int t = 0; t < 4; ++t) {
        const int c0 = t * 16 + quad * 4;
#pragma unroll
        for (int r = 0; r < 4; ++r) {
          int ga = a0[t] + r * GT + ((c0 + r > cth) ? 1 : 0);
          sv[t][r] = __builtin_amdgcn_exp2f(sv[t][r] + bf2f(Gbt[ga]));
        }
      }
    }

    // ---- V fragments (B-operand: V[key][d], d = dt*16+lidx)
    short8 vb[4][2];
#pragma unroll
    for (int dt = 0; dt < 4; ++dt) {
      const char* VtT = (const char*)Vt + dt * 2048;
      vb[dt][0] = bfrag(VtT, lidx, quad, 0);
      vb[dt][1] = bfrag(VtT, lidx, quad, 1);
    }

    // ---- pack P to bf16 + in-register quad redistribution -> PV A-frags
    // af[kb] elem j = P[row=lidx][key kb*32+quad*8+j]
    short8 af[2];
#pragma unroll
    for (int kb = 0; kb < 2; ++kb) {
      uint mm[4];
#pragma unroll
      for (int i = 0; i < 2; ++i) {
        uint e, o;
        asm("v_cvt_pk_bf16_f32 %0, %1, %2" : "=v"(e) : "v"(sv[2 * kb][2 * i]),     "v"(sv[2 * kb][2 * i + 1]));
        asm("v_cvt_pk_bf16_f32 %0, %1, %2" : "=v"(o) : "v"(sv[2 * kb + 1][2 * i]), "v"(sv[2 * kb + 1][2 * i + 1]));
        asm("v_permlane32_swap_b32 %0, %1" : "+v"(e), "+v"(o));
        asm("v_permlane16_swap_b32 %0, %1" : "+v"(e), "+v"(o));
        mm[i] = e; mm[2 + i] = o;
      }
      union { uint u[4]; short8 s; } cv;
      cv.u[0] = mm[0]; cv.u[1] = mm[1]; cv.u[2] = mm[2]; cv.u[3] = mm[3];
      af[kb] = cv.s;
    }

    __syncthreads();   // B2: all LDS consumed; KRe(jt+1) DMA drained

    if (jt + 1 < jt1) {
      stageV(jt + 1);   // DMA overlaps PV + next AC/G; drains at next B1
      fixup(jt + 1);
    }

    // ---- PV + li (pure registers): O[wave's rows][all d]
#pragma unroll
    for (int dt = 0; dt < 4; ++dt) {
      oacc[dt] = __builtin_amdgcn_mfma_f32_16x16x32_bf16(af[0], vb[dt][0], oacc[dt], 0, 0, 0);
      oacc[dt] = __builtin_amdgcn_mfma_f32_16x16x32_bf16(af[1], vb[dt][1], oacc[dt], 0, 0, 0);
    }
    liacc = __builtin_amdgcn_mfma_f32_16x16x32_bf16(af[0], ones8, liacc, 0, 0, 0);
    liacc = __builtin_amdgcn_mfma_f32_16x16x32_bf16(af[1], ones8, liacc, 0, 0, 0);
  }

  // ---- epilogue: plain stores to this chunk's disjoint partial buffer
  float* __restrict__ Oc = (chunk == 0) ? O0 : (chunk == 1 ? O1 : O2);
  float* __restrict__ Lc = Lp + chunk * (16 * T_);
  const int rowg0 = (b * 8 + n) * T_ + i0 + wave * 16 + quad * 4;
#pragma unroll
  for (int reg = 0; reg < 4; ++reg) {
    int rowg = rowg0 + reg;
#pragma unroll
    for (int dt = 0; dt < 4; ++dt)
      Oc[(size_t)rowg * 64 + dt * 16 + lidx] = oacc[dt][reg];
    if (lidx == 0) Lc[rowg] = liacc[reg];
  }
}

// ---------------------------------------------------------------- sum partials, normalize -> avec bf16
__global__ __launch_bounds__(256) void attn_norm_kernel(
    const float* __restrict__ O0, const float* __restrict__ O1,
    const float* __restrict__ O2, const float* __restrict__ Lp,
    ushort* __restrict__ avec)
{
  int idx = blockIdx.x * 256 + threadIdx.x;   // over [bn][row][d4], 16*2048*16
  int d4  = idx & 15;
  int row = (idx >> 4) & 2047;
  int bn  = idx >> 15;
  float4 v0 = ((const float4*)O0)[idx];
  float4 v1 = ((const float4*)O1)[idx];
  float4 v2 = ((const float4*)O2)[idx];
  int rg = (bn << 11) + row;
  float li = Lp[rg] + Lp[rg + 16 * T_] + Lp[rg + 32 * T_];
  float inv = 1.0f / li;
  int b = bn >> 3, n = bn & 7;
  ushort4 w = { f2bf((v0.x + v1.x + v2.x) * inv), f2bf((v0.y + v1.y + v2.y) * inv),
                f2bf((v0.z + v1.z + v2.z) * inv), f2bf((v0.w + v1.w + v2.w) * inv) };
  *(ushort4*)&avec[(size_t)(row * 2 + b) * DM + n * 64 + d4 * 4] = w;
}

// ---------------------------------------------------------------- LN(residual), dual out
__global__ __launch_bounds__(256) void ln_res_kernel(
    float* __restrict__ h, ushort* __restrict__ hb, const float* __restrict__ delta,
    const float* __restrict__ s, const float* __restrict__ bb)
{
  const int m = blockIdx.x;
  const int tid = threadIdx.x;
  float* hp = h + (size_t)m * DM;
  ushort* hbp = hb + (size_t)m * DM;
  const float* dp = delta + (size_t)m * DM;
  float x0 = hp[tid] + dp[tid];
  float x1 = hp[tid + 256] + dp[tid + 256];
  float sum = x0 + x1, sq = x0 * x0 + x1 * x1;
#pragma unroll
  for (int o = 32; o > 0; o >>= 1) { sum += __shfl_down(sum, o); sq += __shfl_down(sq, o); }
  __shared__ float part[8];
  int wv = tid >> 6;
  if ((tid & 63) == 0) { part[wv * 2] = sum; part[wv * 2 + 1] = sq; }
  __syncthreads();
  float ts = part[0] + part[2] + part[4] + part[6];
  float tq = part[1] + part[3] + part[5] + part[7];
  float mu = ts * (1.f / DM);
  float var = tq * (1.f / DM) - mu * mu;
  float rs = rsqrtf(var + 1e-5f);
  float y0 = (x0 - mu) * rs * s[tid]       + bb[tid];
  float y1 = (x1 - mu) * rs * s[tid + 256] + bb[tid + 256];
  hp[tid] = y0;       hbp[tid] = f2bf(y0);
  hp[tid + 256] = y1; hbp[tid + 256] = f2bf(y1);
}

// ---------------------------------------------------------------- classifier reorder
__global__ __launch_bounds__(256) void reorder_kernel(const float* __restrict__ ct,
                                                      float* __restrict__ out) {
  int idx = blockIdx.x * 256 + threadIdx.x;
  if (idx >= B_ * NCLS * T_) return;
  int t  = idx & (T_ - 1);
  int nc = (idx >> 11) & 63;
  int bb = idx >> 17;
  out[idx] = ct[(size_t)(t * B_ + bb) * NCLS + nc];
}

// ---------------------------------------------------------------- launch
extern "C" void kernel_launch(void* const* d_in, const int* in_sizes, int n_in,
                              void* d_out, int out_size, void* d_ws, size_t ws_size,
                              hipStream_t stream)
{
  const float* x     = (const float*)d_in[0];
  const float* emb_w = (const float*)d_in[1];
  const float* emb_b = (const float*)d_in[2];
  const float* rwb   = (const float*)d_in[3];
  const float* rrb   = (const float*)d_in[4];
  const float* qkv_w = (const float*)d_in[5];
  const float* qkv_b = (const float*)d_in[6];
  const float* rproj = (const float*)d_in[7];
  const float* o_w   = (const float*)d_in[8];
  const float* ln1s  = (const float*)d_in[9];
  const float* ln1b  = (const float*)d_in[10];
  const float* ff1w  = (const float*)d_in[11];
  const float* ff1b  = (const float*)d_in[12];
  const float* ff2w  = (const float*)d_in[13];
  const float* ff2b  = (const float*)d_in[14];
  const float* ln2s  = (const float*)d_in[15];
  const float* ln2b  = (const float*)d_in[16];
  const float* clsw  = (const float*)d_in[17];
  const float* clsb  = (const float*)d_in[18];
  float* out = (float*)d_out;

  char* p = (char*)d_ws;
  float*  h       = (float*)p;   p += (size_t)MT * DM * 4;
  float*  tmpf    = (float*)p;   p += (size_t)MT * DM * 4;
  ushort* hb      = (ushort*)p;  p += (size_t)MT * DM * 2;
  ushort* headsb  = (ushort*)p;  p += (size_t)MT * 1536 * 2;
  ushort* peb     = (ushort*)p;  p += (size_t)T_ * DM * 2;
  ushort* rk_all  = (ushort*)p;  p += (size_t)T_ * 2048 * 2;
  ushort* avecb   = (ushort*)p;  p += (size_t)MT * DM * 2;
  ushort* xfb     = (ushort*)p;  p += (size_t)MT * INCH * 2;
  ushort* emb_wb  = (ushort*)p;  p += (size_t)DM * INCH * 2;
  ushort* qkv_wb  = (ushort*)p;  p += (size_t)4 * 1536 * DM * 2;
  ushort* rproj_wb= (ushort*)p;  p += (size_t)4 * DM * DM * 2;
  ushort* o_wb    = (ushort*)p;  p += (size_t)4 * DM * DM * 2;
  ushort* ff1_wb  = (ushort*)p;  p += (size_t)4 * DI * DM * 2;
  ushort* ff2_wb  = (ushort*)p;  p += (size_t)4 * DM * DI * 2;
  float*  P2      = (float*)p;   p += (size_t)MT * DM * 4;   // chunk-2 O partial
  float*  Lp      = (float*)p;   p += (size_t)3 * 16 * T_ * 4;
  ushort* vtg     = xfb;   // region reused; live only vtrans->attn
  // chunk-0 partial = tmpf (free during attn); chunk-1 partial = xfb tail
  // (xfb is 16 MB; vtg uses only the first 4 MB; ff1 rewrites xfb later).
  float*  P0      = tmpf;
  float*  P1      = (float*)(xfb + (size_t)16 * 64 * T_);   // xfb + 4 MB

  cvt6_kernel<<<dim3(4096, 6), 256, 0, stream>>>(
      emb_w, emb_wb, DM * INCH / 4,
      qkv_w, qkv_wb, 4 * 1536 * DM / 4,
      rproj, rproj_wb, 4 * DM * DM / 4,
      o_w,   o_wb,   4 * DM * DM / 4,
      ff1w,  ff1_wb, 4 * DI * DM / 4,
      ff2w,  ff2_wb, 4 * DM * DI / 4);
  pos_kernel<<<(T_ * DM) / 256, 256, 0, stream>>>(peb);
  xpose_kernel<<<dim3(T_ / 32, INCH / 32, B_), 256, 0, stream>>>(x, xfb);

  gemm_bf16<64, 2, false><<<dim3(DM / 128, MT / 64), 256, 0, stream>>>(
      xfb, emb_wb, emb_b, h, hb, MT, DM, INCH);
  gemm_bf16<128, 1, false><<<dim3(2048 / 128, T_ / 128), 256, 0, stream>>>(
      peb, rproj_wb, nullptr, nullptr, rk_all, T_, 2048, DM);

  for (int l = 0; l < 4; ++l) {
    gemm_bf16<128, 1, false><<<dim3(1536 / 128, MT / 128), 256, 0, stream>>>(
        hb, qkv_wb + (size_t)l * 1536 * DM, qkv_b + l * 1536, nullptr, headsb, MT, 1536, DM);
    vtrans_kernel<<<dim3(T_ / 64, B_ * NH), 256, 0, stream>>>(headsb, vtg);
    attn_mfma_kernel<<<dim3(T_ / 64, B_ * NH, 3), 256, 0, stream>>>(
        headsb, rk_all + (size_t)l * 512, vtg, rwb, rrb, P0, P1, P2, Lp);
    attn_norm_kernel<<<(16 * T_ * 16) / 256, 256, 0, stream>>>(P0, P1, P2, Lp, avecb);
    gemm_bf16<32, 0, false><<<dim3(DM / 128, MT / 32), 256, 0, stream>>>(
        avecb, o_wb + (size_t)l * DM * DM, nullptr, tmpf, nullptr, MT, DM, DM);
    ln_res_kernel<<<MT, 256, 0, stream>>>(h, hb, tmpf, ln1s + l * DM, ln1b + l * DM);
    gemm_bf16<128, 1, true><<<dim3(DI / 128, MT / 128), 256, 0, stream>>>(
        hb, ff1_wb + (size_t)l * DI * DM, ff1b + l * DI, nullptr, xfb, MT, DI, DM);
    gemm_bf16<32, 0, false><<<dim3(DM / 128, MT / 32), 256, 0, stream>>>(
        xfb, ff2_wb + (size_t)l * DM * DI, ff2b + l * DM, tmpf, nullptr, MT, DM, DI);
    ln_res_kernel<<<MT, 256, 0, stream>>>(h, hb, tmpf, ln2s + l * DM, ln2b + l * DM);
  }

  gemm_f32<<<dim3(1, MT / BM), 256, 0, stream>>>(h, clsw, clsb, tmpf, MT, NCLS, DM);
  reorder_kernel<<<(B_ * NCLS * T_) / 256, 256, 0, stream>>>(tmpf, out);
}

// Round 5
// 848.202 us; speedup vs baseline: 1.1135x; 1.0726x over previous
//
#include <hip/hip_runtime.h>
#include <hip/hip_bf16.h>
#include <math.h>

// TransformerXL forward. bf16-MFMA GEMMs (BK=64, swizzled) + swapped-operand
// flash rel-attention, split-K over key-tiles (3 chunks, grid 1536 = 2 perfect
// rounds at 3 blocks/CU): S^T = mfma(K,Q), P lane-local, in-register pack via
// v_cvt_pk_bf16_f32 + permlane{32,16}_swap; no-max softmax => chunk partials
// (O, li) to disjoint buffers (plain stores); norm kernel sums and emits bf16.
// Classifier runs on the bf16 MFMA path (W zero-padded 64->128 cols).
// Layout: [t,b,*] flattened, m = t*B_ + b.

#define T_   2048
#define B_   2
#define DM   512
#define NH   8
#define DH   64
#define DI   2048
#define INCH 2048
#define NCLS 64
#define MT   4096   // T_*B_

typedef __attribute__((ext_vector_type(8))) short short8;
typedef __attribute__((ext_vector_type(4))) float float4v;

#define QSCALE 0.1803368801111204f   // 0.125 * log2(e)

__device__ inline ushort f2bf(float f) {
  uint u = __float_as_uint(f);
  return (ushort)((u + 0x7FFFu + ((u >> 16) & 1u)) >> 16);   // RNE
}
__device__ inline float bf2f(ushort h) { return __uint_as_float(((uint)h) << 16); }
__device__ inline uint pkbf(float a, float b) {
  __hip_bfloat162 h = __float22bfloat162_rn(float2{a, b});
  return *(uint*)&h;
}
__device__ inline void gload16(const void* g, void* lds) {
  __builtin_amdgcn_global_load_lds(
      (const __attribute__((address_space(1))) void*)g,
      (__attribute__((address_space(3))) void*)lds, 16, 0, 0);
}

// ---------------------------------------------------------------- pos emb (bf16 out)
__global__ __launch_bounds__(256) void pos_kernel(ushort* __restrict__ pe) {
  int idx = blockIdx.x * 256 + threadIdx.x;
  if (idx >= T_ * DM) return;
  int t = idx >> 9;
  int i = idx & 511;
  int j = (i < 256) ? i : (i - 256);
  double invf = exp(-(double)(2 * j) * (9.210340371976184 / 512.0));
  double a = (double)(T_ - 1 - t) * invf;
  pe[idx] = f2bf((i < 256) ? (float)sin(a) : (float)cos(a));
}

// ---------------------------------------------------------------- fused fp32->bf16 (6 segments)
__global__ __launch_bounds__(256) void cvt6_kernel(
    const float* s0, ushort* d0, int n0,
    const float* s1, ushort* d1, int n1,
    const float* s2, ushort* d2, int n2,
    const float* s3, ushort* d3, int n3,
    const float* s4, ushort* d4, int n4,
    const float* s5, ushort* d5, int n5)
{
  const float* s; ushort* d; int n;
  switch (blockIdx.y) {
    case 0: s = s0; d = d0; n = n0; break;
    case 1: s = s1; d = d1; n = n1; break;
    case 2: s = s2; d = d2; n = n2; break;
    case 3: s = s3; d = d3; n = n3; break;
    case 4: s = s4; d = d4; n = n4; break;
    default: s = s5; d = d5; n = n5; break;
  }
  int i = blockIdx.x * 256 + threadIdx.x;
  if (i >= n) return;
  float4 v = ((const float4*)s)[i];
  ushort4 w = { f2bf(v.x), f2bf(v.y), f2bf(v.z), f2bf(v.w) };
  ((ushort4*)d)[i] = w;
}

// ---------------------------------------------------------------- clsw f32[64][512] -> bf16[128][512] zero-padded
__global__ __launch_bounds__(256) void clsw_cvt_kernel(const float* __restrict__ w,
                                                       ushort* __restrict__ wb) {
  int i = blockIdx.x * 256 + threadIdx.x;   // 16384 ushort4 groups = 128*512/4
  ushort4 o;
  if (i < 8192) {   // rows 0..63
    float4 v = ((const float4*)w)[i];
    o = ushort4{ f2bf(v.x), f2bf(v.y), f2bf(v.z), f2bf(v.w) };
  } else {
    o = ushort4{ 0, 0, 0, 0 };
  }
  ((ushort4*)wb)[i] = o;
}

// ---------------------------------------------------------------- x[B,C,T] -> xb[(t*2+b), C] bf16
__global__ __launch_bounds__(256) void xpose_kernel(const float* __restrict__ x,
                                                    ushort* __restrict__ xb) {
  __shared__ float s[32][33];
  int t0 = blockIdx.x * 32, k0 = blockIdx.y * 32, b = blockIdx.z;
  int tx = threadIdx.x & 31, ty = threadIdx.x >> 5;
#pragma unroll
  for (int l = 0; l < 4; ++l) {
    int k = k0 + ty + l * 8;
    s[ty + l * 8][tx] = x[((size_t)b * INCH + k) * T_ + t0 + tx];
  }
  __syncthreads();
#pragma unroll
  for (int l = 0; l < 4; ++l) {
    int t = t0 + ty + l * 8;
    xb[((size_t)(t * 2 + b)) * INCH + k0 + tx] = f2bf(s[tx][ty + l * 8]);
  }
}

// ---------------------------------------------------------------- V transpose per layer
// heads V section (t,b,n,d) -> vtg[((b*8+n)*64+d)][t]
__global__ __launch_bounds__(256) void vtrans_kernel(const ushort* __restrict__ heads,
                                                     ushort* __restrict__ vtg) {
  __shared__ ushort s[64][72];
  const int tid = threadIdx.x;
  int t0 = blockIdx.x * 64;
  int b = blockIdx.y & 1, n = blockIdx.y >> 1;
  for (int e = tid; e < 512; e += 256) {
    int r = e >> 3, c = e & 7;
    *(uint4*)&s[r][c * 8] =
        *(const uint4*)&heads[(size_t)((t0 + r) * 2 + b) * 1536 + 1024 + n * 64 + c * 8];
  }
  __syncthreads();
  for (int e = tid; e < 512; e += 256) {
    int d = e >> 3, c = e & 7;
    ushort tmp[8];
#pragma unroll
    for (int j = 0; j < 8; ++j) tmp[j] = s[c * 8 + j][d];
    *(uint4*)&vtg[((size_t)((b * 8 + n) * 64 + d)) * (size_t)T_ + t0 + c * 8] = *(uint4*)tmp;
  }
}

// ---------------------------------------------------------------- bf16 MFMA GEMM (BK=64)
template<int TM, int OUTMODE, bool RELU>
__global__ __launch_bounds__(256) void gemm_bf16(
    const ushort* __restrict__ A, const ushort* __restrict__ W,
    const float* __restrict__ bias, float* __restrict__ Cf, ushort* __restrict__ Cb,
    int M, int N, int K)
{
  __shared__ __attribute__((aligned(16))) ushort As[TM * 64];
  __shared__ __attribute__((aligned(16))) ushort Bs[128 * 64];
  const int NI = TM / 32;
  const int tid  = threadIdx.x;
  const int wave = tid >> 6, lane = tid & 63;
  const int quad = lane >> 4, lidx = lane & 15;
  const int m0 = blockIdx.y * TM, n0 = blockIdx.x * 128;
  const int r8 = lane >> 3;
  const int cs = ((lane & 7) ^ (r8 & 7)) * 8;

  float4v acc[NI * 4];
#pragma unroll
  for (int i = 0; i < NI * 4; ++i) acc[i] = (float4v){0.f, 0.f, 0.f, 0.f};

  const int wm = (wave >> 1) * (TM / 2), wn = (wave & 1) * 64;

  for (int k0 = 0; k0 < K; k0 += 64) {
    __syncthreads();
#pragma unroll
    for (int g = 0; g < TM / 32; ++g) {
      int r0 = wave * 8 + g * 32;
      gload16(A + (size_t)(m0 + r0 + r8) * K + k0 + cs, &As[r0 * 64]);
    }
#pragma unroll
    for (int g = 0; g < 4; ++g) {
      int r0 = wave * 8 + g * 32;
      gload16(W + (size_t)(n0 + r0 + r8) * K + k0 + cs, &Bs[r0 * 64]);
    }
    __syncthreads();

#pragma unroll
    for (int kb = 0; kb < 2; ++kb) {
      short8 af[NI], bf4[4];
      const int ch = (((kb * 4 + quad) ^ (lidx & 7)) * 8);
#pragma unroll
      for (int i = 0; i < NI; ++i)
        af[i] = *(const short8*)&As[(wm + i * 16 + lidx) * 64 + ch];
#pragma unroll
      for (int j = 0; j < 4; ++j)
        bf4[j] = *(const short8*)&Bs[(wn + j * 16 + lidx) * 64 + ch];
#pragma unroll
      for (int i = 0; i < NI; ++i)
#pragma unroll
        for (int j = 0; j < 4; ++j)
          acc[i * 4 + j] = __builtin_amdgcn_mfma_f32_16x16x32_bf16(af[i], bf4[j], acc[i * 4 + j], 0, 0, 0);
    }
  }

  float bj[4];
#pragma unroll
  for (int j = 0; j < 4; ++j) bj[j] = bias ? bias[n0 + wn + j * 16 + lidx] : 0.f;
#pragma unroll
  for (int i = 0; i < NI; ++i) {
    int rbase = m0 + wm + i * 16 + quad * 4;
#pragma unroll
    for (int j = 0; j < 4; ++j) {
      int col = n0 + wn + j * 16 + lidx;
#pragma unroll
      for (int reg = 0; reg < 4; ++reg) {
        float v = acc[i * 4 + j][reg] + bj[j];
        if (RELU) v = fmaxf(v, 0.f);
        size_t off = (size_t)(rbase + reg) * N + col;
        if (OUTMODE != 1) Cf[off] = v;
        if (OUTMODE != 0) Cb[off] = f2bf(v);
      }
    }
  }
}

// ---------------------------------------------------------------- MFMA flash rel-attn (swapped, split-K)
// Grid z = 3 key-chunks (jt in {[0,11),[11,22),[22,32)}); grid 1536 -> 2 perfect
// rounds at 3 blocks/CU. Block: 64 q-rows of one (b,n); wave owns q-row strip.
// AC swapped: S^T = mfma(K, Q) -> thread holds S[key][row=lidx] lane-local.
// rel_shift gather from Gbt; sel = (w > wth) classified block-uniform:
// all-sel (wth<0) / no-sel (wth>=126) fast paths, per-element only for the
// <=2 mixed iterations. No-max base-2 softmax in regs (raw v_exp_f32);
// P packed via v_cvt_pk_bf16_f32 + permlane{32,16}_swap. PV swapped;
// O/li chunk partials go to disjoint per-chunk buffers (plain stores).
#define GT 68

__device__ inline short8 bfrag(const char* base, int lidx, int quad, int kb) {
  return *(const short8*)(base + lidx * 128 + ((((kb << 2) + quad) ^ (lidx & 7)) << 4));
}

__global__ __launch_bounds__(256, 3) void attn_mfma_kernel(
    const ushort* __restrict__ heads, const ushort* __restrict__ rk,
    const ushort* __restrict__ vtg,
    const float* __restrict__ rwb, const float* __restrict__ rrb,
    float* __restrict__ O0, float* __restrict__ O1, float* __restrict__ O2,
    float* __restrict__ Lp)
{
  __shared__ __attribute__((aligned(16))) ushort Ks[64 * 64];    // swizzled [key][d]
  __shared__ __attribute__((aligned(16))) ushort Vt[64 * 64];    // swizzled [d][key]
  __shared__ __attribute__((aligned(16))) ushort Re[128 * 64];   // swizzled [w][d]
  __shared__ __attribute__((aligned(16))) ushort Gbt[128 * GT];  // [w][grow]

  const int tid  = threadIdx.x;
  const int i0   = blockIdx.x * 64;
  const int b    = blockIdx.y & 1;
  const int n    = blockIdx.y >> 1;
  const int chunk = blockIdx.z;
  const int jt0 = (chunk == 0) ? 0  : (chunk == 1 ? 11 : 22);
  const int jt1 = (chunk == 0) ? 11 : (chunk == 1 ? 22 : 32);
  const int wave = tid >> 6;
  const int lane = tid & 63;
  const int quad = lane >> 4;
  const int lidx = lane & 15;
  const int r8   = lane >> 3;
  const int cs8  = ((lane & 7) ^ (r8 & 7)) * 8;
  const int bn64 = (b * 8 + n) * 64;
  const int rloc = wave * 16 + lidx;   // this thread's q-row within block

  // ---- Q fragments in registers.
  short8 qw[2], qr4[4][2], q4[2];
  {
    auto qfrag = [&](int row, int kb, const float* bias) -> short8 {
      short8 q;
      if (row < T_) q = *(const short8*)&heads[(size_t)(row * 2 + b) * 1536 + n * 64 + kb * 32 + quad * 8];
      else { for (int t = 0; t < 8; ++t) ((ushort*)&q)[t] = 0; }
      short8 o;
#pragma unroll
      for (int t = 0; t < 8; ++t) {
        float f = (bf2f((ushort)((ushort*)&q)[t]) + bias[n * 64 + kb * 32 + quad * 8 + t]) * QSCALE;
        ((ushort*)&o)[t] = f2bf(f);
      }
      return o;
    };
    qw[0] = qfrag(i0 + rloc, 0, rwb);
    qw[1] = qfrag(i0 + rloc, 1, rwb);
#pragma unroll
    for (int rt = 0; rt < 4; ++rt) {
      int row = i0 + rt * 16 + lidx;
      qr4[rt][0] = qfrag(row, 0, rrb); qr4[rt][1] = qfrag(row, 1, rrb);
    }
    int row4 = i0 + 64 + lidx;
    q4[0] = qfrag(row4, 0, rrb); q4[1] = qfrag(row4, 1, rrb);
  }

  // loop-invariant gather bases: per ktile t, addr of Gbt[w(c0)][rloc]
  int a0[4];
#pragma unroll
  for (int t = 0; t < 4; ++t)
    a0[t] = (t * 16 + quad * 4 + 63 - rloc) * GT + rloc;

  float4v oacc[4];
  float4v liacc = (float4v){0.f, 0.f, 0.f, 0.f};
#pragma unroll
  for (int dt = 0; dt < 4; ++dt) oacc[dt] = (float4v){0.f, 0.f, 0.f, 0.f};
  short8 ones8;
#pragma unroll
  for (int t = 0; t < 8; ++t) ((ushort*)&ones8)[t] = 0x3F80;   // bf16 1.0

  auto stageKRe = [&](int jt) {
    int j0 = jt * 64, qmin = j0 + 1984 - i0;
#pragma unroll
    for (int half = 0; half < 2; ++half) {
      int r0 = 8 * wave + 32 * half;
      gload16(heads + (size_t)((j0 + r0 + r8) * 2 + b) * 1536 + 512 + n * 64 + cs8, &Ks[r0 * 64]);
    }
#pragma unroll
    for (int q4i = 0; q4i < 4; ++q4i) {
      int r0 = 8 * wave + 32 * q4i;
      int qh = qmin + r0 + r8;
      int p  = (qh > T_) ? (qh - T_ - 1) : ((qh == T_) ? 0 : qh);
      gload16(rk + (size_t)p * 2048 + n * 64 + cs8, &Re[r0 * 64]);
    }
  };
  auto stageV = [&](int jt) {
    int j0 = jt * 64;
#pragma unroll
    for (int half = 0; half < 2; ++half) {
      int r0 = 8 * wave + 32 * half;
      gload16(vtg + (size_t)(bn64 + r0 + r8) * (size_t)T_ + j0 + cs8, &Vt[r0 * 64]);
    }
  };
  auto fixup = [&](int jt) {   // zero Rext[T] row (after DMA drained)
    int qmin = jt * 64 + 1984 - i0;
    int Tidx = T_ - qmin;
    if (Tidx >= 0 && Tidx < 128) {
      if (tid < 32) ((uint*)Re)[Tidx * 32 + tid] = 0u;
      __syncthreads();
    }
  };

  stageKRe(jt0);
  stageV(jt0);
  __syncthreads();
  fixup(jt0);

  for (int jt = jt0; jt < jt1; ++jt) {
    const int qmin = jt * 64 + 1984 - i0;
    const int wth  = T_ - qmin;   // sel = (w > wth)

    // ---- AC swapped: sv[t][reg] = S[key t*16+quad*4+reg][row lidx(=rloc)]
    float4v sv[4];
#pragma unroll
    for (int t = 0; t < 4; ++t) {
      const char* KsT = (const char*)Ks + t * 2048;
      short8 kf0 = bfrag(KsT, lidx, quad, 0);
      short8 kf1 = bfrag(KsT, lidx, quad, 1);
      float4v c = {0.f, 0.f, 0.f, 0.f};
      c = __builtin_amdgcn_mfma_f32_16x16x32_bf16(kf0, qw[0], c, 0, 0, 0);
      c = __builtin_amdgcn_mfma_f32_16x16x32_bf16(kf1, qw[1], c, 0, 0, 0);
      sv[t] = c;
    }

    // ---- G: strips {wave, wave+4}; C: col->w, row->grow; aligned uint2 stores
#pragma unroll
    for (int si = 0; si < 2; ++si) {
      const int ws = wave + si * 4;
      const int w0 = ws * 16;
      const char* ReW = (const char*)Re + w0 * 128;
      short8 rb0 = bfrag(ReW, lidx, quad, 0);
      short8 rb1 = bfrag(ReW, lidx, quad, 1);
#pragma unroll
      for (int rt = 0; rt < 4; ++rt) {
        bool need = si == 0 ? (rt >= 3 - wave) : (rt <= 3 - wave);
        if (need) {
          float4v g = {0.f, 0.f, 0.f, 0.f};
          g = __builtin_amdgcn_mfma_f32_16x16x32_bf16(qr4[rt][0], rb0, g, 0, 0, 0);
          g = __builtin_amdgcn_mfma_f32_16x16x32_bf16(qr4[rt][1], rb1, g, 0, 0, 0);
          uint2 st; st.x = pkbf(g[0], g[1]); st.y = pkbf(g[2], g[3]);
          *(uint2*)&Gbt[(w0 + lidx) * GT + rt * 16 + quad * 4] = st;
        }
      }
      if (si == 0 && wth < 63) {   // grow=64 row (for sel at r=63), strips w<64
        float4v g = {0.f, 0.f, 0.f, 0.f};
        g = __builtin_amdgcn_mfma_f32_16x16x32_bf16(q4[0], rb0, g, 0, 0, 0);
        g = __builtin_amdgcn_mfma_f32_16x16x32_bf16(q4[1], rb1, g, 0, 0, 0);
        if (quad == 0) Gbt[(w0 + lidx) * GT + 64] = f2bf(g[0]);
      }
    }
    __syncthreads();   // B1: Gbt ready; Ks/Re consumed; Vt(jt) DMA drained

    if (jt + 1 < jt1) stageKRe(jt + 1);   // DMA overlaps gather; drains at B2

    // ---- gather BD + no-max base-2 softmax, in registers (raw v_exp_f32)
    // sel = (c > cth) is block-uniform-classifiable: no-sel iff wth>=126,
    // all-sel iff wth<0; mixed hits <=2 iterations per block.
    if (wth >= 126) {
#pragma unroll
      for (int t = 0; t < 4; ++t)
#pragma unroll
        for (int r = 0; r < 4; ++r)
          sv[t][r] = __builtin_amdgcn_exp2f(sv[t][r] + bf2f(Gbt[a0[t] + r * GT]));
    } else if (wth < 0) {
#pragma unroll
      for (int t = 0; t < 4; ++t)
#pragma unroll
        for (int r = 0; r < 4; ++r)
          sv[t][r] = __builtin_amdgcn_exp2f(sv[t][r] + bf2f(Gbt[a0[t] + r * GT + 1]));
    } else {
      const int cth = wth + rloc - 63;   // sel = (c > cth)
#pragma unroll
      for (int t = 0; t < 4; ++t) {
        const int c0 = t * 16 + quad * 4;
#pragma unroll
        for (int r = 0; r < 4; ++r) {
          int ga = a0[t] + r * GT + ((c0 + r > cth) ? 1 : 0);
          sv[t][r] = __builtin_amdgcn_exp2f(sv[t][r] + bf2f(Gbt[ga]));
        }
      }
    }

    // ---- V fragments (B-operand: V[key][d], d = dt*16+lidx)
    short8 vb[4][2];
#pragma unroll
    for (int dt = 0; dt < 4; ++dt) {
      const char* VtT = (const char*)Vt + dt * 2048;
      vb[dt][0] = bfrag(VtT, lidx, quad, 0);
      vb[dt][1] = bfrag(VtT, lidx, quad, 1);
    }

    // ---- pack P to bf16 + in-register quad redistribution -> PV A-frags
    // af[kb] elem j = P[row=lidx][key kb*32+quad*8+j]
    short8 af[2];
#pragma unroll
    for (int kb = 0; kb < 2; ++kb) {
      uint mm[4];
#pragma unroll
      for (int i = 0; i < 2; ++i) {
        uint e, o;
        asm("v_cvt_pk_bf16_f32 %0, %1, %2" : "=v"(e) : "v"(sv[2 * kb][2 * i]),     "v"(sv[2 * kb][2 * i + 1]));
        asm("v_cvt_pk_bf16_f32 %0, %1, %2" : "=v"(o) : "v"(sv[2 * kb + 1][2 * i]), "v"(sv[2 * kb + 1][2 * i + 1]));
        asm("v_permlane32_swap_b32 %0, %1" : "+v"(e), "+v"(o));
        asm("v_permlane16_swap_b32 %0, %1" : "+v"(e), "+v"(o));
        mm[i] = e; mm[2 + i] = o;
      }
      union { uint u[4]; short8 s; } cv;
      cv.u[0] = mm[0]; cv.u[1] = mm[1]; cv.u[2] = mm[2]; cv.u[3] = mm[3];
      af[kb] = cv.s;
    }

    __syncthreads();   // B2: all LDS consumed; KRe(jt+1) DMA drained

    if (jt + 1 < jt1) {
      stageV(jt + 1);   // DMA overlaps PV + next AC/G; drains at next B1
      fixup(jt + 1);
    }

    // ---- PV + li (pure registers): O[wave's rows][all d]
#pragma unroll
    for (int dt = 0; dt < 4; ++dt) {
      oacc[dt] = __builtin_amdgcn_mfma_f32_16x16x32_bf16(af[0], vb[dt][0], oacc[dt], 0, 0, 0);
      oacc[dt] = __builtin_amdgcn_mfma_f32_16x16x32_bf16(af[1], vb[dt][1], oacc[dt], 0, 0, 0);
    }
    liacc = __builtin_amdgcn_mfma_f32_16x16x32_bf16(af[0], ones8, liacc, 0, 0, 0);
    liacc = __builtin_amdgcn_mfma_f32_16x16x32_bf16(af[1], ones8, liacc, 0, 0, 0);
  }

  // ---- epilogue: plain stores to this chunk's disjoint partial buffer
  float* __restrict__ Oc = (chunk == 0) ? O0 : (chunk == 1 ? O1 : O2);
  float* __restrict__ Lc = Lp + chunk * (16 * T_);
  const int rowg0 = (b * 8 + n) * T_ + i0 + wave * 16 + quad * 4;
#pragma unroll
  for (int reg = 0; reg < 4; ++reg) {
    int rowg = rowg0 + reg;
#pragma unroll
    for (int dt = 0; dt < 4; ++dt)
      Oc[(size_t)rowg * 64 + dt * 16 + lidx] = oacc[dt][reg];
    if (lidx == 0) Lc[rowg] = liacc[reg];
  }
}

// ---------------------------------------------------------------- sum partials, normalize -> avec bf16
__global__ __launch_bounds__(256) void attn_norm_kernel(
    const float* __restrict__ O0, const float* __restrict__ O1,
    const float* __restrict__ O2, const float* __restrict__ Lp,
    ushort* __restrict__ avec)
{
  int idx = blockIdx.x * 256 + threadIdx.x;   // over [bn][row][d4], 16*2048*16
  int d4  = idx & 15;
  int row = (idx >> 4) & 2047;
  int bn  = idx >> 15;
  float4 v0 = ((const float4*)O0)[idx];
  float4 v1 = ((const float4*)O1)[idx];
  float4 v2 = ((const float4*)O2)[idx];
  int rg = (bn << 11) + row;
  float li = Lp[rg] + Lp[rg + 16 * T_] + Lp[rg + 32 * T_];
  float inv = 1.0f / li;
  int b = bn >> 3, n = bn & 7;
  ushort4 w = { f2bf((v0.x + v1.x + v2.x) * inv), f2bf((v0.y + v1.y + v2.y) * inv),
                f2bf((v0.z + v1.z + v2.z) * inv), f2bf((v0.w + v1.w + v2.w) * inv) };
  *(ushort4*)&avec[(size_t)(row * 2 + b) * DM + n * 64 + d4 * 4] = w;
}

// ---------------------------------------------------------------- LN(residual), dual out
__global__ __launch_bounds__(256) void ln_res_kernel(
    float* __restrict__ h, ushort* __restrict__ hb, const float* __restrict__ delta,
    const float* __restrict__ s, const float* __restrict__ bb)
{
  const int m = blockIdx.x;
  const int tid = threadIdx.x;
  float* hp = h + (size_t)m * DM;
  ushort* hbp = hb + (size_t)m * DM;
  const float* dp = delta + (size_t)m * DM;
  float x0 = hp[tid] + dp[tid];
  float x1 = hp[tid + 256] + dp[tid + 256];
  float sum = x0 + x1, sq = x0 * x0 + x1 * x1;
#pragma unroll
  for (int o = 32; o > 0; o >>= 1) { sum += __shfl_down(sum, o); sq += __shfl_down(sq, o); }
  __shared__ float part[8];
  int wv = tid >> 6;
  if ((tid & 63) == 0) { part[wv * 2] = sum; part[wv * 2 + 1] = sq; }
  __syncthreads();
  float ts = part[0] + part[2] + part[4] + part[6];
  float tq = part[1] + part[3] + part[5] + part[7];
  float mu = ts * (1.f / DM);
  float var = tq * (1.f / DM) - mu * mu;
  float rs = rsqrtf(var + 1e-5f);
  float y0 = (x0 - mu) * rs * s[tid]       + bb[tid];
  float y1 = (x1 - mu) * rs * s[tid + 256] + bb[tid + 256];
  hp[tid] = y0;       hbp[tid] = f2bf(y0);
  hp[tid + 256] = y1; hbp[tid + 256] = f2bf(y1);
}

// ---------------------------------------------------------------- classifier reorder (+bias)
__global__ __launch_bounds__(256) void reorder_kernel(const float* __restrict__ ct,
                                                      const float* __restrict__ cb,
                                                      float* __restrict__ out) {
  int idx = blockIdx.x * 256 + threadIdx.x;
  if (idx >= B_ * NCLS * T_) return;
  int t  = idx & (T_ - 1);
  int nc = (idx >> 11) & 63;
  int bb = idx >> 17;
  out[idx] = ct[(size_t)(t * B_ + bb) * 128 + nc] + cb[nc];
}

// ---------------------------------------------------------------- launch
extern "C" void kernel_launch(void* const* d_in, const int* in_sizes, int n_in,
                              void* d_out, int out_size, void* d_ws, size_t ws_size,
                              hipStream_t stream)
{
  const float* x     = (const float*)d_in[0];
  const float* emb_w = (const float*)d_in[1];
  const float* emb_b = (const float*)d_in[2];
  const float* rwb   = (const float*)d_in[3];
  const float* rrb   = (const float*)d_in[4];
  const float* qkv_w = (const float*)d_in[5];
  const float* qkv_b = (const float*)d_in[6];
  const float* rproj = (const float*)d_in[7];
  const float* o_w   = (const float*)d_in[8];
  const float* ln1s  = (const float*)d_in[9];
  const float* ln1b  = (const float*)d_in[10];
  const float* ff1w  = (const float*)d_in[11];
  const float* ff1b  = (const float*)d_in[12];
  const float* ff2w  = (const float*)d_in[13];
  const float* ff2b  = (const float*)d_in[14];
  const float* ln2s  = (const float*)d_in[15];
  const float* ln2b  = (const float*)d_in[16];
  const float* clsw  = (const float*)d_in[17];
  const float* clsb  = (const float*)d_in[18];
  float* out = (float*)d_out;

  char* p = (char*)d_ws;
  float*  h       = (float*)p;   p += (size_t)MT * DM * 4;
  float*  tmpf    = (float*)p;   p += (size_t)MT * DM * 4;
  ushort* hb      = (ushort*)p;  p += (size_t)MT * DM * 2;
  ushort* headsb  = (ushort*)p;  p += (size_t)MT * 1536 * 2;
  ushort* peb     = (ushort*)p;  p += (size_t)T_ * DM * 2;
  ushort* rk_all  = (ushort*)p;  p += (size_t)T_ * 2048 * 2;
  ushort* avecb   = (ushort*)p;  p += (size_t)MT * DM * 2;
  ushort* xfb     = (ushort*)p;  p += (size_t)MT * INCH * 2;
  ushort* emb_wb  = (ushort*)p;  p += (size_t)DM * INCH * 2;
  ushort* qkv_wb  = (ushort*)p;  p += (size_t)4 * 1536 * DM * 2;
  ushort* rproj_wb= (ushort*)p;  p += (size_t)4 * DM * DM * 2;
  ushort* o_wb    = (ushort*)p;  p += (size_t)4 * DM * DM * 2;
  ushort* ff1_wb  = (ushort*)p;  p += (size_t)4 * DI * DM * 2;
  ushort* ff2_wb  = (ushort*)p;  p += (size_t)4 * DM * DI * 2;
  float*  P2      = (float*)p;   p += (size_t)MT * DM * 4;   // chunk-2 O partial
  float*  Lp      = (float*)p;   p += (size_t)3 * 16 * T_ * 4;
  ushort* cls_wb  = (ushort*)p;  p += (size_t)128 * DM * 2;  // zero-padded bf16 clsw
  ushort* vtg     = xfb;   // region reused; live only vtrans->attn
  // chunk-0 partial = tmpf (free during attn); chunk-1 partial = xfb tail
  // (xfb is 16 MB; vtg uses only the first 4 MB; ff1 rewrites xfb later).
  float*  P0      = tmpf;
  float*  P1      = (float*)(xfb + (size_t)16 * 64 * T_);   // xfb + 4 MB

  cvt6_kernel<<<dim3(4096, 6), 256, 0, stream>>>(
      emb_w, emb_wb, DM * INCH / 4,
      qkv_w, qkv_wb, 4 * 1536 * DM / 4,
      rproj, rproj_wb, 4 * DM * DM / 4,
      o_w,   o_wb,   4 * DM * DM / 4,
      ff1w,  ff1_wb, 4 * DI * DM / 4,
      ff2w,  ff2_wb, 4 * DM * DI / 4);
  clsw_cvt_kernel<<<64, 256, 0, stream>>>(clsw, cls_wb);
  pos_kernel<<<(T_ * DM) / 256, 256, 0, stream>>>(peb);
  xpose_kernel<<<dim3(T_ / 32, INCH / 32, B_), 256, 0, stream>>>(x, xfb);

  gemm_bf16<64, 2, false><<<dim3(DM / 128, MT / 64), 256, 0, stream>>>(
      xfb, emb_wb, emb_b, h, hb, MT, DM, INCH);
  gemm_bf16<128, 1, false><<<dim3(2048 / 128, T_ / 128), 256, 0, stream>>>(
      peb, rproj_wb, nullptr, nullptr, rk_all, T_, 2048, DM);

  for (int l = 0; l < 4; ++l) {
    gemm_bf16<128, 1, false><<<dim3(1536 / 128, MT / 128), 256, 0, stream>>>(
        hb, qkv_wb + (size_t)l * 1536 * DM, qkv_b + l * 1536, nullptr, headsb, MT, 1536, DM);
    vtrans_kernel<<<dim3(T_ / 64, B_ * NH), 256, 0, stream>>>(headsb, vtg);
    attn_mfma_kernel<<<dim3(T_ / 64, B_ * NH, 3), 256, 0, stream>>>(
        headsb, rk_all + (size_t)l * 512, vtg, rwb, rrb, P0, P1, P2, Lp);
    attn_norm_kernel<<<(16 * T_ * 16) / 256, 256, 0, stream>>>(P0, P1, P2, Lp, avecb);
    gemm_bf16<32, 0, false><<<dim3(DM / 128, MT / 32), 256, 0, stream>>>(
        avecb, o_wb + (size_t)l * DM * DM, nullptr, tmpf, nullptr, MT, DM, DM);
    ln_res_kernel<<<MT, 256, 0, stream>>>(h, hb, tmpf, ln1s + l * DM, ln1b + l * DM);
    gemm_bf16<128, 1, true><<<dim3(DI / 128, MT / 128), 256, 0, stream>>>(
        hb, ff1_wb + (size_t)l * DI * DM, ff1b + l * DI, nullptr, xfb, MT, DI, DM);
    gemm_bf16<32, 0, false><<<dim3(DM / 128, MT / 32), 256, 0, stream>>>(
        xfb, ff2_wb + (size_t)l * DM * DI, ff2b + l * DM, tmpf, nullptr, MT, DM, DI);
    ln_res_kernel<<<MT, 256, 0, stream>>>(h, hb, tmpf, ln2s + l * DM, ln2b + l * DM);
  }

  // classifier: bf16 MFMA, N padded to 128 (rows 64.. are zero); bias in reorder
  gemm_bf16<32, 0, false><<<dim3(1, MT / 32), 256, 0, stream>>>(
      hb, cls_wb, nullptr, tmpf, nullptr, MT, 128, DM);
  reorder_kernel<<<(B_ * NCLS * T_) / 256, 256, 0, stream>>>(tmpf, clsb, out);
}

// Round 7
// 842.728 us; speedup vs baseline: 1.1208x; 1.0065x over previous
//
#include <hip/hip_runtime.h>
#include <hip/hip_bf16.h>
#include <math.h>

// TransformerXL forward. bf16-MFMA GEMMs (BK=64, swizzled) + swapped-operand
// flash rel-attention, split-K over key-tiles (3 chunks, grid 1536 = 2 perfect
// rounds at 3 blocks/CU): S^T = mfma(K,Q), P lane-local, in-register pack via
// v_cvt_pk_bf16_f32 + permlane{32,16}_swap; no-max softmax => chunk partials
// (O, li) to disjoint buffers (plain stores); norm kernel sums and emits bf16.
// PV runs BEFORE B2 (register-only) so the KRe(jt+1) DMA drain at B2 is
// covered by gather+pack+PV instead of gather+pack only.
// Classifier runs on the bf16 MFMA path (W zero-padded 64->128 cols).
// Layout: [t,b,*] flattened, m = t*B_ + b.

#define T_   2048
#define B_   2
#define DM   512
#define NH   8
#define DH   64
#define DI   2048
#define INCH 2048
#define NCLS 64
#define MT   4096   // T_*B_

typedef __attribute__((ext_vector_type(8))) short short8;
typedef __attribute__((ext_vector_type(4))) float float4v;

#define QSCALE 0.1803368801111204f   // 0.125 * log2(e)

__device__ inline ushort f2bf(float f) {
  uint u = __float_as_uint(f);
  return (ushort)((u + 0x7FFFu + ((u >> 16) & 1u)) >> 16);   // RNE
}
__device__ inline float bf2f(ushort h) { return __uint_as_float(((uint)h) << 16); }
__device__ inline uint pkbf(float a, float b) {
  __hip_bfloat162 h = __float22bfloat162_rn(float2{a, b});
  return *(uint*)&h;
}
__device__ inline void gload16(const void* g, void* lds) {
  __builtin_amdgcn_global_load_lds(
      (const __attribute__((address_space(1))) void*)g,
      (__attribute__((address_space(3))) void*)lds, 16, 0, 0);
}

// ---------------------------------------------------------------- pos emb (bf16 out)
__global__ __launch_bounds__(256) void pos_kernel(ushort* __restrict__ pe) {
  int idx = blockIdx.x * 256 + threadIdx.x;
  if (idx >= T_ * DM) return;
  int t = idx >> 9;
  int i = idx & 511;
  int j = (i < 256) ? i : (i - 256);
  double invf = exp(-(double)(2 * j) * (9.210340371976184 / 512.0));
  double a = (double)(T_ - 1 - t) * invf;
  pe[idx] = f2bf((i < 256) ? (float)sin(a) : (float)cos(a));
}

// ---------------------------------------------------------------- fused fp32->bf16 (6 segments)
__global__ __launch_bounds__(256) void cvt6_kernel(
    const float* s0, ushort* d0, int n0,
    const float* s1, ushort* d1, int n1,
    const float* s2, ushort* d2, int n2,
    const float* s3, ushort* d3, int n3,
    const float* s4, ushort* d4, int n4,
    const float* s5, ushort* d5, int n5)
{
  const float* s; ushort* d; int n;
  switch (blockIdx.y) {
    case 0: s = s0; d = d0; n = n0; break;
    case 1: s = s1; d = d1; n = n1; break;
    case 2: s = s2; d = d2; n = n2; break;
    case 3: s = s3; d = d3; n = n3; break;
    case 4: s = s4; d = d4; n = n4; break;
    default: s = s5; d = d5; n = n5; break;
  }
  int i = blockIdx.x * 256 + threadIdx.x;
  if (i >= n) return;
  float4 v = ((const float4*)s)[i];
  ushort4 w = { f2bf(v.x), f2bf(v.y), f2bf(v.z), f2bf(v.w) };
  ((ushort4*)d)[i] = w;
}

// ---------------------------------------------------------------- clsw f32[64][512] -> bf16[128][512] zero-padded
__global__ __launch_bounds__(256) void clsw_cvt_kernel(const float* __restrict__ w,
                                                       ushort* __restrict__ wb) {
  int i = blockIdx.x * 256 + threadIdx.x;   // 16384 ushort4 groups = 128*512/4
  ushort4 o;
  if (i < 8192) {   // rows 0..63
    float4 v = ((const float4*)w)[i];
    o = ushort4{ f2bf(v.x), f2bf(v.y), f2bf(v.z), f2bf(v.w) };
  } else {
    o = ushort4{ 0, 0, 0, 0 };
  }
  ((ushort4*)wb)[i] = o;
}

// ---------------------------------------------------------------- x[B,C,T] -> xb[(t*2+b), C] bf16
__global__ __launch_bounds__(256) void xpose_kernel(const float* __restrict__ x,
                                                    ushort* __restrict__ xb) {
  __shared__ float s[32][33];
  int t0 = blockIdx.x * 32, k0 = blockIdx.y * 32, b = blockIdx.z;
  int tx = threadIdx.x & 31, ty = threadIdx.x >> 5;
#pragma unroll
  for (int l = 0; l < 4; ++l) {
    int k = k0 + ty + l * 8;
    s[ty + l * 8][tx] = x[((size_t)b * INCH + k) * T_ + t0 + tx];
  }
  __syncthreads();
#pragma unroll
  for (int l = 0; l < 4; ++l) {
    int t = t0 + ty + l * 8;
    xb[((size_t)(t * 2 + b)) * INCH + k0 + tx] = f2bf(s[tx][ty + l * 8]);
  }
}

// ---------------------------------------------------------------- V transpose per layer
// heads V section (t,b,n,d) -> vtg[((b*8+n)*64+d)][t]
__global__ __launch_bounds__(256) void vtrans_kernel(const ushort* __restrict__ heads,
                                                     ushort* __restrict__ vtg) {
  __shared__ ushort s[64][72];
  const int tid = threadIdx.x;
  int t0 = blockIdx.x * 64;
  int b = blockIdx.y & 1, n = blockIdx.y >> 1;
  for (int e = tid; e < 512; e += 256) {
    int r = e >> 3, c = e & 7;
    *(uint4*)&s[r][c * 8] =
        *(const uint4*)&heads[(size_t)((t0 + r) * 2 + b) * 1536 + 1024 + n * 64 + c * 8];
  }
  __syncthreads();
  for (int e = tid; e < 512; e += 256) {
    int d = e >> 3, c = e & 7;
    ushort tmp[8];
#pragma unroll
    for (int j = 0; j < 8; ++j) tmp[j] = s[c * 8 + j][d];
    *(uint4*)&vtg[((size_t)((b * 8 + n) * 64 + d)) * (size_t)T_ + t0 + c * 8] = *(uint4*)tmp;
  }
}

// ---------------------------------------------------------------- bf16 MFMA GEMM (BK=64)
template<int TM, int OUTMODE, bool RELU>
__global__ __launch_bounds__(256) void gemm_bf16(
    const ushort* __restrict__ A, const ushort* __restrict__ W,
    const float* __restrict__ bias, float* __restrict__ Cf, ushort* __restrict__ Cb,
    int M, int N, int K)
{
  __shared__ __attribute__((aligned(16))) ushort As[TM * 64];
  __shared__ __attribute__((aligned(16))) ushort Bs[128 * 64];
  const int NI = TM / 32;
  const int tid  = threadIdx.x;
  const int wave = tid >> 6, lane = tid & 63;
  const int quad = lane >> 4, lidx = lane & 15;
  const int m0 = blockIdx.y * TM, n0 = blockIdx.x * 128;
  const int r8 = lane >> 3;
  const int cs = ((lane & 7) ^ (r8 & 7)) * 8;

  float4v acc[NI * 4];
#pragma unroll
  for (int i = 0; i < NI * 4; ++i) acc[i] = (float4v){0.f, 0.f, 0.f, 0.f};

  const int wm = (wave >> 1) * (TM / 2), wn = (wave & 1) * 64;

  for (int k0 = 0; k0 < K; k0 += 64) {
    __syncthreads();
#pragma unroll
    for (int g = 0; g < TM / 32; ++g) {
      int r0 = wave * 8 + g * 32;
      gload16(A + (size_t)(m0 + r0 + r8) * K + k0 + cs, &As[r0 * 64]);
    }
#pragma unroll
    for (int g = 0; g < 4; ++g) {
      int r0 = wave * 8 + g * 32;
      gload16(W + (size_t)(n0 + r0 + r8) * K + k0 + cs, &Bs[r0 * 64]);
    }
    __syncthreads();

#pragma unroll
    for (int kb = 0; kb < 2; ++kb) {
      short8 af[NI], bf4[4];
      const int ch = (((kb * 4 + quad) ^ (lidx & 7)) * 8);
#pragma unroll
      for (int i = 0; i < NI; ++i)
        af[i] = *(const short8*)&As[(wm + i * 16 + lidx) * 64 + ch];
#pragma unroll
      for (int j = 0; j < 4; ++j)
        bf4[j] = *(const short8*)&Bs[(wn + j * 16 + lidx) * 64 + ch];
#pragma unroll
      for (int i = 0; i < NI; ++i)
#pragma unroll
        for (int j = 0; j < 4; ++j)
          acc[i * 4 + j] = __builtin_amdgcn_mfma_f32_16x16x32_bf16(af[i], bf4[j], acc[i * 4 + j], 0, 0, 0);
    }
  }

  float bj[4];
#pragma unroll
  for (int j = 0; j < 4; ++j) bj[j] = bias ? bias[n0 + wn + j * 16 + lidx] : 0.f;
#pragma unroll
  for (int i = 0; i < NI; ++i) {
    int rbase = m0 + wm + i * 16 + quad * 4;
#pragma unroll
    for (int j = 0; j < 4; ++j) {
      int col = n0 + wn + j * 16 + lidx;
#pragma unroll
      for (int reg = 0; reg < 4; ++reg) {
        float v = acc[i * 4 + j][reg] + bj[j];
        if (RELU) v = fmaxf(v, 0.f);
        size_t off = (size_t)(rbase + reg) * N + col;
        if (OUTMODE != 1) Cf[off] = v;
        if (OUTMODE != 0) Cb[off] = f2bf(v);
      }
    }
  }
}

// ---------------------------------------------------------------- MFMA flash rel-attn (swapped, split-K)
// Grid z = 3 key-chunks (jt in {[0,11),[11,22),[22,32)}); grid 1536 -> 2 perfect
// rounds at 3 blocks/CU. Block: 64 q-rows of one (b,n); wave owns q-row strip.
// AC swapped: S^T = mfma(K, Q) -> thread holds S[key][row=lidx] lane-local.
// rel_shift gather from Gbt; sel = (w > wth) classified block-uniform:
// all-sel (wth<0) / no-sel (wth>=126) fast paths, per-element only for the
// <=2 mixed iterations. No-max base-2 softmax in regs (raw v_exp_f32);
// P packed via v_cvt_pk_bf16_f32 + permlane{32,16}_swap. PV swapped and
// register-only => scheduled BEFORE B2 to lengthen the KRe DMA shadow.
// O/li chunk partials go to disjoint per-chunk buffers (plain stores).
#define GT 68

__device__ inline short8 bfrag(const char* base, int lidx, int quad, int kb) {
  return *(const short8*)(base + lidx * 128 + ((((kb << 2) + quad) ^ (lidx & 7)) << 4));
}

__global__ __launch_bounds__(256, 3) void attn_mfma_kernel(
    const ushort* __restrict__ heads, const ushort* __restrict__ rk,
    const ushort* __restrict__ vtg,
    const float* __restrict__ rwb, const float* __restrict__ rrb,
    float* __restrict__ O0, float* __restrict__ O1, float* __restrict__ O2,
    float* __restrict__ Lp)
{
  __shared__ __attribute__((aligned(16))) ushort Ks[64 * 64];    // swizzled [key][d]
  __shared__ __attribute__((aligned(16))) ushort Vt[64 * 64];    // swizzled [d][key]
  __shared__ __attribute__((aligned(16))) ushort Re[128 * 64];   // swizzled [w][d]
  __shared__ __attribute__((aligned(16))) ushort Gbt[128 * GT];  // [w][grow]

  const int tid  = threadIdx.x;
  const int i0   = blockIdx.x * 64;
  const int b    = blockIdx.y & 1;
  const int n    = blockIdx.y >> 1;
  const int chunk = blockIdx.z;
  const int jt0 = (chunk == 0) ? 0  : (chunk == 1 ? 11 : 22);
  const int jt1 = (chunk == 0) ? 11 : (chunk == 1 ? 22 : 32);
  const int wave = tid >> 6;
  const int lane = tid & 63;
  const int quad = lane >> 4;
  const int lidx = lane & 15;
  const int r8   = lane >> 3;
  const int cs8  = ((lane & 7) ^ (r8 & 7)) * 8;
  const int bn64 = (b * 8 + n) * 64;
  const int rloc = wave * 16 + lidx;   // this thread's q-row within block

  // ---- Q fragments in registers.
  short8 qw[2], qr4[4][2], q4[2];
  {
    auto qfrag = [&](int row, int kb, const float* bias) -> short8 {
      short8 q;
      if (row < T_) q = *(const short8*)&heads[(size_t)(row * 2 + b) * 1536 + n * 64 + kb * 32 + quad * 8];
      else { for (int t = 0; t < 8; ++t) ((ushort*)&q)[t] = 0; }
      short8 o;
#pragma unroll
      for (int t = 0; t < 8; ++t) {
        float f = (bf2f((ushort)((ushort*)&q)[t]) + bias[n * 64 + kb * 32 + quad * 8 + t]) * QSCALE;
        ((ushort*)&o)[t] = f2bf(f);
      }
      return o;
    };
    qw[0] = qfrag(i0 + rloc, 0, rwb);
    qw[1] = qfrag(i0 + rloc, 1, rwb);
#pragma unroll
    for (int rt = 0; rt < 4; ++rt) {
      int row = i0 + rt * 16 + lidx;
      qr4[rt][0] = qfrag(row, 0, rrb); qr4[rt][1] = qfrag(row, 1, rrb);
    }
    int row4 = i0 + 64 + lidx;
    q4[0] = qfrag(row4, 0, rrb); q4[1] = qfrag(row4, 1, rrb);
  }

  // loop-invariant gather bases: per ktile t, addr of Gbt[w(c0)][rloc]
  int a0[4];
#pragma unroll
  for (int t = 0; t < 4; ++t)
    a0[t] = (t * 16 + quad * 4 + 63 - rloc) * GT + rloc;

  float4v oacc[4];
  float4v liacc = (float4v){0.f, 0.f, 0.f, 0.f};
#pragma unroll
  for (int dt = 0; dt < 4; ++dt) oacc[dt] = (float4v){0.f, 0.f, 0.f, 0.f};
  short8 ones8;
#pragma unroll
  for (int t = 0; t < 8; ++t) ((ushort*)&ones8)[t] = 0x3F80;   // bf16 1.0

  auto stageKRe = [&](int jt) {
    int j0 = jt * 64, qmin = j0 + 1984 - i0;
#pragma unroll
    for (int half = 0; half < 2; ++half) {
      int r0 = 8 * wave + 32 * half;
      gload16(heads + (size_t)((j0 + r0 + r8) * 2 + b) * 1536 + 512 + n * 64 + cs8, &Ks[r0 * 64]);
    }
#pragma unroll
    for (int q4i = 0; q4i < 4; ++q4i) {
      int r0 = 8 * wave + 32 * q4i;
      int qh = qmin + r0 + r8;
      int p  = (qh > T_) ? (qh - T_ - 1) : ((qh == T_) ? 0 : qh);
      gload16(rk + (size_t)p * 2048 + n * 64 + cs8, &Re[r0 * 64]);
    }
  };
  auto stageV = [&](int jt) {
    int j0 = jt * 64;
#pragma unroll
    for (int half = 0; half < 2; ++half) {
      int r0 = 8 * wave + 32 * half;
      gload16(vtg + (size_t)(bn64 + r0 + r8) * (size_t)T_ + j0 + cs8, &Vt[r0 * 64]);
    }
  };
  auto fixup = [&](int jt) {   // zero Rext[T] row (after DMA drained)
    int qmin = jt * 64 + 1984 - i0;
    int Tidx = T_ - qmin;
    if (Tidx >= 0 && Tidx < 128) {
      if (tid < 32) ((uint*)Re)[Tidx * 32 + tid] = 0u;
      __syncthreads();   // orders the write before next iter's G reads of Re
    }
  };

  stageKRe(jt0);
  stageV(jt0);
  __syncthreads();
  fixup(jt0);

  for (int jt = jt0; jt < jt1; ++jt) {
    const int qmin = jt * 64 + 1984 - i0;
    const int wth  = T_ - qmin;   // sel = (w > wth)

    // ---- AC swapped: sv[t][reg] = S[key t*16+quad*4+reg][row lidx(=rloc)]
    float4v sv[4];
#pragma unroll
    for (int t = 0; t < 4; ++t) {
      const char* KsT = (const char*)Ks + t * 2048;
      short8 kf0 = bfrag(KsT, lidx, quad, 0);
      short8 kf1 = bfrag(KsT, lidx, quad, 1);
      float4v c = {0.f, 0.f, 0.f, 0.f};
      c = __builtin_amdgcn_mfma_f32_16x16x32_bf16(kf0, qw[0], c, 0, 0, 0);
      c = __builtin_amdgcn_mfma_f32_16x16x32_bf16(kf1, qw[1], c, 0, 0, 0);
      sv[t] = c;
    }

    // ---- G: strips {wave, wave+4}; C: col->w, row->grow; aligned uint2 stores
#pragma unroll
    for (int si = 0; si < 2; ++si) {
      const int ws = wave + si * 4;
      const int w0 = ws * 16;
      const char* ReW = (const char*)Re + w0 * 128;
      short8 rb0 = bfrag(ReW, lidx, quad, 0);
      short8 rb1 = bfrag(ReW, lidx, quad, 1);
#pragma unroll
      for (int rt = 0; rt < 4; ++rt) {
        bool need = si == 0 ? (rt >= 3 - wave) : (rt <= 3 - wave);
        if (need) {
          float4v g = {0.f, 0.f, 0.f, 0.f};
          g = __builtin_amdgcn_mfma_f32_16x16x32_bf16(qr4[rt][0], rb0, g, 0, 0, 0);
          g = __builtin_amdgcn_mfma_f32_16x16x32_bf16(qr4[rt][1], rb1, g, 0, 0, 0);
          uint2 st; st.x = pkbf(g[0], g[1]); st.y = pkbf(g[2], g[3]);
          *(uint2*)&Gbt[(w0 + lidx) * GT + rt * 16 + quad * 4] = st;
        }
      }
      if (si == 0 && wth < 63) {   // grow=64 row (for sel at r=63), strips w<64
        float4v g = {0.f, 0.f, 0.f, 0.f};
        g = __builtin_amdgcn_mfma_f32_16x16x32_bf16(q4[0], rb0, g, 0, 0, 0);
        g = __builtin_amdgcn_mfma_f32_16x16x32_bf16(q4[1], rb1, g, 0, 0, 0);
        if (quad == 0) Gbt[(w0 + lidx) * GT + 64] = f2bf(g[0]);
      }
    }
    __syncthreads();   // B1: Gbt ready; Ks/Re consumed; Vt(jt) DMA drained

    if (jt + 1 < jt1) stageKRe(jt + 1);   // DMA overlaps gather+pack+PV; drains at B2

    // ---- gather BD + no-max base-2 softmax, in registers (raw v_exp_f32)
    // sel = (c > cth) is block-uniform-classifiable: no-sel iff wth>=126,
    // all-sel iff wth<0; mixed hits <=2 iterations per block.
    if (wth >= 126) {
#pragma unroll
      for (int t = 0; t < 4; ++t)
#pragma unroll
        for (int r = 0; r < 4; ++r)
          sv[t][r] = __builtin_amdgcn_exp2f(sv[t][r] + bf2f(Gbt[a0[t] + r * GT]));
    } else if (wth < 0) {
#pragma unroll
      for (int t = 0; t < 4; ++t)
#pragma unroll
        for (int r = 0; r < 4; ++r)
          sv[t][r] = __builtin_amdgcn_exp2f(sv[t][r] + bf2f(Gbt[a0[t] + r * GT + 1]));
    } else {
      const int cth = wth + rloc - 63;   // sel = (c > cth)
#pragma unroll
      for (int t = 0; t < 4; ++t) {
        const int c0 = t * 16 + quad * 4;
#pragma unroll
        for (int r = 0; r < 4; ++r) {
          int ga = a0[t] + r * GT + ((c0 + r > cth) ? 1 : 0);
          sv[t][r] = __builtin_amdgcn_exp2f(sv[t][r] + bf2f(Gbt[ga]));
        }
      }
    }

    // ---- V fragments (B-operand: V[key][d], d = dt*16+lidx)
    short8 vb[4][2];
#pragma unroll
    for (int dt = 0; dt < 4; ++dt) {
      const char* VtT = (const char*)Vt + dt * 2048;
      vb[dt][0] = bfrag(VtT, lidx, quad, 0);
      vb[dt][1] = bfrag(VtT, lidx, quad, 1);
    }

    // ---- pack P to bf16 + in-register quad redistribution -> PV A-frags
    // af[kb] elem j = P[row=lidx][key kb*32+quad*8+j]
    short8 af[2];
#pragma unroll
    for (int kb = 0; kb < 2; ++kb) {
      uint mm[4];
#pragma unroll
      for (int i = 0; i < 2; ++i) {
        uint e, o;
        asm("v_cvt_pk_bf16_f32 %0, %1, %2" : "=v"(e) : "v"(sv[2 * kb][2 * i]),     "v"(sv[2 * kb][2 * i + 1]));
        asm("v_cvt_pk_bf16_f32 %0, %1, %2" : "=v"(o) : "v"(sv[2 * kb + 1][2 * i]), "v"(sv[2 * kb + 1][2 * i + 1]));
        asm("v_permlane32_swap_b32 %0, %1" : "+v"(e), "+v"(o));
        asm("v_permlane16_swap_b32 %0, %1" : "+v"(e), "+v"(o));
        mm[i] = e; mm[2 + i] = o;
      }
      union { uint u[4]; short8 s; } cv;
      cv.u[0] = mm[0]; cv.u[1] = mm[1]; cv.u[2] = mm[2]; cv.u[3] = mm[3];
      af[kb] = cv.s;
    }

    // ---- PV + li (pure registers, no LDS): before B2 to extend KRe shadow
#pragma unroll
    for (int dt = 0; dt < 4; ++dt) {
      oacc[dt] = __builtin_amdgcn_mfma_f32_16x16x32_bf16(af[0], vb[dt][0], oacc[dt], 0, 0, 0);
      oacc[dt] = __builtin_amdgcn_mfma_f32_16x16x32_bf16(af[1], vb[dt][1], oacc[dt], 0, 0, 0);
    }
    liacc = __builtin_amdgcn_mfma_f32_16x16x32_bf16(af[0], ones8, liacc, 0, 0, 0);
    liacc = __builtin_amdgcn_mfma_f32_16x16x32_bf16(af[1], ones8, liacc, 0, 0, 0);

    __syncthreads();   // B2: Gbt/Vt consumed; KRe(jt+1) DMA drained

    if (jt + 1 < jt1) {
      stageV(jt + 1);   // DMA overlaps next AC/G; drains at next B1
      fixup(jt + 1);
    }
  }

  // ---- epilogue: plain stores to this chunk's disjoint partial buffer
  float* __restrict__ Oc = (chunk == 0) ? O0 : (chunk == 1 ? O1 : O2);
  float* __restrict__ Lc = Lp + chunk * (16 * T_);
  const int rowg0 = (b * 8 + n) * T_ + i0 + wave * 16 + quad * 4;
#pragma unroll
  for (int reg = 0; reg < 4; ++reg) {
    int rowg = rowg0 + reg;
#pragma unroll
    for (int dt = 0; dt < 4; ++dt)
      Oc[(size_t)rowg * 64 + dt * 16 + lidx] = oacc[dt][reg];
    if (lidx == 0) Lc[rowg] = liacc[reg];
  }
}

// ---------------------------------------------------------------- sum partials, normalize -> avec bf16
__global__ __launch_bounds__(256) void attn_norm_kernel(
    const float* __restrict__ O0, const float* __restrict__ O1,
    const float* __restrict__ O2, const float* __restrict__ Lp,
    ushort* __restrict__ avec)
{
  int idx = blockIdx.x * 256 + threadIdx.x;   // over [bn][row][d4], 16*2048*16
  int d4  = idx & 15;
  int row = (idx >> 4) & 2047;
  int bn  = idx >> 15;
  float4 v0 = ((const float4*)O0)[idx];
  float4 v1 = ((const float4*)O1)[idx];
  float4 v2 = ((const float4*)O2)[idx];
  int rg = (bn << 11) + row;
  float li = Lp[rg] + Lp[rg + 16 * T_] + Lp[rg + 32 * T_];
  float inv = 1.0f / li;
  int b = bn >> 3, n = bn & 7;
  ushort4 w = { f2bf((v0.x + v1.x + v2.x) * inv), f2bf((v0.y + v1.y + v2.y) * inv),
                f2bf((v0.z + v1.z + v2.z) * inv), f2bf((v0.w + v1.w + v2.w) * inv) };
  *(ushort4*)&avec[(size_t)(row * 2 + b) * DM + n * 64 + d4 * 4] = w;
}

// ---------------------------------------------------------------- LN(residual), dual out
__global__ __launch_bounds__(256) void ln_res_kernel(
    float* __restrict__ h, ushort* __restrict__ hb, const float* __restrict__ delta,
    const float* __restrict__ s, const float* __restrict__ bb)
{
  const int m = blockIdx.x;
  const int tid = threadIdx.x;
  float* hp = h + (size_t)m * DM;
  ushort* hbp = hb + (size_t)m * DM;
  const float* dp = delta + (size_t)m * DM;
  float x0 = hp[tid] + dp[tid];
  float x1 = hp[tid + 256] + dp[tid + 256];
  float sum = x0 + x1, sq = x0 * x0 + x1 * x1;
#pragma unroll
  for (int o = 32; o > 0; o >>= 1) { sum += __shfl_down(sum, o); sq += __shfl_down(sq, o); }
  __shared__ float part[8];
  int wv = tid >> 6;
  if ((tid & 63) == 0) { part[wv * 2] = sum; part[wv * 2 + 1] = sq; }
  __syncthreads();
  float ts = part[0] + part[2] + part[4] + part[6];
  float tq = part[1] + part[3] + part[5] + part[7];
  float mu = ts * (1.f / DM);
  float var = tq * (1.f / DM) - mu * mu;
  float rs = rsqrtf(var + 1e-5f);
  float y0 = (x0 - mu) * rs * s[tid]       + bb[tid];
  float y1 = (x1 - mu) * rs * s[tid + 256] + bb[tid + 256];
  hp[tid] = y0;       hbp[tid] = f2bf(y0);
  hp[tid + 256] = y1; hbp[tid + 256] = f2bf(y1);
}

// ---------------------------------------------------------------- classifier reorder (+bias)
__global__ __launch_bounds__(256) void reorder_kernel(const float* __restrict__ ct,
                                                      const float* __restrict__ cb,
                                                      float* __restrict__ out) {
  int idx = blockIdx.x * 256 + threadIdx.x;
  if (idx >= B_ * NCLS * T_) return;
  int t  = idx & (T_ - 1);
  int nc = (idx >> 11) & 63;
  int bb = idx >> 17;
  out[idx] = ct[(size_t)(t * B_ + bb) * 128 + nc] + cb[nc];
}

// ---------------------------------------------------------------- launch
extern "C" void kernel_launch(void* const* d_in, const int* in_sizes, int n_in,
                              void* d_out, int out_size, void* d_ws, size_t ws_size,
                              hipStream_t stream)
{
  const float* x     = (const float*)d_in[0];
  const float* emb_w = (const float*)d_in[1];
  const float* emb_b = (const float*)d_in[2];
  const float* rwb   = (const float*)d_in[3];
  const float* rrb   = (const float*)d_in[4];
  const float* qkv_w = (const float*)d_in[5];
  const float* qkv_b = (const float*)d_in[6];
  const float* rproj = (const float*)d_in[7];
  const float* o_w   = (const float*)d_in[8];
  const float* ln1s  = (const float*)d_in[9];
  const float* ln1b  = (const float*)d_in[10];
  const float* ff1w  = (const float*)d_in[11];
  const float* ff1b  = (const float*)d_in[12];
  const float* ff2w  = (const float*)d_in[13];
  const float* ff2b  = (const float*)d_in[14];
  const float* ln2s  = (const float*)d_in[15];
  const float* ln2b  = (const float*)d_in[16];
  const float* clsw  = (const float*)d_in[17];
  const float* clsb  = (const float*)d_in[18];
  float* out = (float*)d_out;

  char* p = (char*)d_ws;
  float*  h       = (float*)p;   p += (size_t)MT * DM * 4;
  float*  tmpf    = (float*)p;   p += (size_t)MT * DM * 4;
  ushort* hb      = (ushort*)p;  p += (size_t)MT * DM * 2;
  ushort* headsb  = (ushort*)p;  p += (size_t)MT * 1536 * 2;
  ushort* peb     = (ushort*)p;  p += (size_t)T_ * DM * 2;
  ushort* rk_all  = (ushort*)p;  p += (size_t)T_ * 2048 * 2;
  ushort* avecb   = (ushort*)p;  p += (size_t)MT * DM * 2;
  ushort* xfb     = (ushort*)p;  p += (size_t)MT * INCH * 2;
  ushort* emb_wb  = (ushort*)p;  p += (size_t)DM * INCH * 2;
  ushort* qkv_wb  = (ushort*)p;  p += (size_t)4 * 1536 * DM * 2;
  ushort* rproj_wb= (ushort*)p;  p += (size_t)4 * DM * DM * 2;
  ushort* o_wb    = (ushort*)p;  p += (size_t)4 * DM * DM * 2;
  ushort* ff1_wb  = (ushort*)p;  p += (size_t)4 * DI * DM * 2;
  ushort* ff2_wb  = (ushort*)p;  p += (size_t)4 * DM * DI * 2;
  float*  P2      = (float*)p;   p += (size_t)MT * DM * 4;   // chunk-2 O partial
  float*  Lp      = (float*)p;   p += (size_t)3 * 16 * T_ * 4;
  ushort* cls_wb  = (ushort*)p;  p += (size_t)128 * DM * 2;  // zero-padded bf16 clsw
  ushort* vtg     = xfb;   // region reused; live only vtrans->attn
  // chunk-0 partial = tmpf (free during attn); chunk-1 partial = xfb tail
  // (xfb is 16 MB; vtg uses only the first 4 MB; ff1 rewrites xfb later).
  float*  P0      = tmpf;
  float*  P1      = (float*)(xfb + (size_t)16 * 64 * T_);   // xfb + 4 MB

  cvt6_kernel<<<dim3(4096, 6), 256, 0, stream>>>(
      emb_w, emb_wb, DM * INCH / 4,
      qkv_w, qkv_wb, 4 * 1536 * DM / 4,
      rproj, rproj_wb, 4 * DM * DM / 4,
      o_w,   o_wb,   4 * DM * DM / 4,
      ff1w,  ff1_wb, 4 * DI * DM / 4,
      ff2w,  ff2_wb, 4 * DM * DI / 4);
  clsw_cvt_kernel<<<64, 256, 0, stream>>>(clsw, cls_wb);
  pos_kernel<<<(T_ * DM) / 256, 256, 0, stream>>>(peb);
  xpose_kernel<<<dim3(T_ / 32, INCH / 32, B_), 256, 0, stream>>>(x, xfb);

  gemm_bf16<64, 2, false><<<dim3(DM / 128, MT / 64), 256, 0, stream>>>(
      xfb, emb_wb, emb_b, h, hb, MT, DM, INCH);
  gemm_bf16<128, 1, false><<<dim3(2048 / 128, T_ / 128), 256, 0, stream>>>(
      peb, rproj_wb, nullptr, nullptr, rk_all, T_, 2048, DM);

  for (int l = 0; l < 4; ++l) {
    gemm_bf16<128, 1, false><<<dim3(1536 / 128, MT / 128), 256, 0, stream>>>(
        hb, qkv_wb + (size_t)l * 1536 * DM, qkv_b + l * 1536, nullptr, headsb, MT, 1536, DM);
    vtrans_kernel<<<dim3(T_ / 64, B_ * NH), 256, 0, stream>>>(headsb, vtg);
    attn_mfma_kernel<<<dim3(T_ / 64, B_ * NH, 3), 256, 0, stream>>>(
        headsb, rk_all + (size_t)l * 512, vtg, rwb, rrb, P0, P1, P2, Lp);
    attn_norm_kernel<<<(16 * T_ * 16) / 256, 256, 0, stream>>>(P0, P1, P2, Lp, avecb);
    gemm_bf16<32, 0, false><<<dim3(DM / 128, MT / 32), 256, 0, stream>>>(
        avecb, o_wb + (size_t)l * DM * DM, nullptr, tmpf, nullptr, MT, DM, DM);
    ln_res_kernel<<<MT, 256, 0, stream>>>(h, hb, tmpf, ln1s + l * DM, ln1b + l * DM);
    gemm_bf16<128, 1, true><<<dim3(DI / 128, MT / 128), 256, 0, stream>>>(
        hb, ff1_wb + (size_t)l * DI * DM, ff1b + l * DI, nullptr, xfb, MT, DI, DM);
    gemm_bf16<32, 0, false><<<dim3(DM / 128, MT / 32), 256, 0, stream>>>(
        xfb, ff2_wb + (size_t)l * DM * DI, ff2b + l * DM, tmpf, nullptr, MT, DM, DI);
    ln_res_kernel<<<MT, 256, 0, stream>>>(h, hb, tmpf, ln2s + l * DM, ln2b + l * DM);
  }

  // classifier: bf16 MFMA, N padded to 128 (rows 64.. are zero); bias in reorder
  gemm_bf16<32, 0, false><<<dim3(1, MT / 32), 256, 0, stream>>>(
      hb, cls_wb, nullptr, tmpf, nullptr, MT, 128, DM);
  reorder_kernel<<<(B_ * NCLS * T_) / 256, 256, 0, stream>>>(tmpf, clsb, out);
}

// Round 8
// 832.081 us; speedup vs baseline: 1.1351x; 1.0128x over previous
//
#include <hip/hip_runtime.h>
#include <hip/hip_bf16.h>
#include <math.h>

// TransformerXL forward. bf16-MFMA GEMMs (BK=64, swizzled) + swapped-operand
// flash rel-attention, split-K over key-tiles (3 chunks, grid 1536 = 2 perfect
// rounds at 3 blocks/CU): S^T = mfma(K,Q), P lane-local, in-register pack via
// v_cvt_pk_bf16_f32 + permlane{32,16}_swap; no-max softmax => chunk partials
// (O, li) to disjoint buffers (plain stores); norm kernel sums and emits bf16.
// PV runs BEFORE B2 (register-only). XCD-exact-fit block swizzle: all 96
// blocks of one (b,n) land on one XCD (96 = 32 CUs x 3 blocks) so the ~1 MB
// K/V/rk working set stays in that XCD's private L2 across all re-reads.
// Classifier runs on the bf16 MFMA path (W zero-padded 64->128 cols).
// Layout: [t,b,*] flattened, m = t*B_ + b.

#define T_   2048
#define B_   2
#define DM   512
#define NH   8
#define DH   64
#define DI   2048
#define INCH 2048
#define NCLS 64
#define MT   4096   // T_*B_

typedef __attribute__((ext_vector_type(8))) short short8;
typedef __attribute__((ext_vector_type(4))) float float4v;

#define QSCALE 0.1803368801111204f   // 0.125 * log2(e)

__device__ inline ushort f2bf(float f) {
  uint u = __float_as_uint(f);
  return (ushort)((u + 0x7FFFu + ((u >> 16) & 1u)) >> 16);   // RNE
}
__device__ inline float bf2f(ushort h) { return __uint_as_float(((uint)h) << 16); }
__device__ inline uint pkbf(float a, float b) {
  __hip_bfloat162 h = __float22bfloat162_rn(float2{a, b});
  return *(uint*)&h;
}
__device__ inline void gload16(const void* g, void* lds) {
  __builtin_amdgcn_global_load_lds(
      (const __attribute__((address_space(1))) void*)g,
      (__attribute__((address_space(3))) void*)lds, 16, 0, 0);
}

// ---------------------------------------------------------------- pos emb (bf16 out)
__global__ __launch_bounds__(256) void pos_kernel(ushort* __restrict__ pe) {
  int idx = blockIdx.x * 256 + threadIdx.x;
  if (idx >= T_ * DM) return;
  int t = idx >> 9;
  int i = idx & 511;
  int j = (i < 256) ? i : (i - 256);
  double invf = exp(-(double)(2 * j) * (9.210340371976184 / 512.0));
  double a = (double)(T_ - 1 - t) * invf;
  pe[idx] = f2bf((i < 256) ? (float)sin(a) : (float)cos(a));
}

// ---------------------------------------------------------------- fused fp32->bf16 (6 segments)
__global__ __launch_bounds__(256) void cvt6_kernel(
    const float* s0, ushort* d0, int n0,
    const float* s1, ushort* d1, int n1,
    const float* s2, ushort* d2, int n2,
    const float* s3, ushort* d3, int n3,
    const float* s4, ushort* d4, int n4,
    const float* s5, ushort* d5, int n5)
{
  const float* s; ushort* d; int n;
  switch (blockIdx.y) {
    case 0: s = s0; d = d0; n = n0; break;
    case 1: s = s1; d = d1; n = n1; break;
    case 2: s = s2; d = d2; n = n2; break;
    case 3: s = s3; d = d3; n = n3; break;
    case 4: s = s4; d = d4; n = n4; break;
    default: s = s5; d = d5; n = n5; break;
  }
  int i = blockIdx.x * 256 + threadIdx.x;
  if (i >= n) return;
  float4 v = ((const float4*)s)[i];
  ushort4 w = { f2bf(v.x), f2bf(v.y), f2bf(v.z), f2bf(v.w) };
  ((ushort4*)d)[i] = w;
}

// ---------------------------------------------------------------- clsw f32[64][512] -> bf16[128][512] zero-padded
__global__ __launch_bounds__(256) void clsw_cvt_kernel(const float* __restrict__ w,
                                                       ushort* __restrict__ wb) {
  int i = blockIdx.x * 256 + threadIdx.x;   // 16384 ushort4 groups = 128*512/4
  ushort4 o;
  if (i < 8192) {   // rows 0..63
    float4 v = ((const float4*)w)[i];
    o = ushort4{ f2bf(v.x), f2bf(v.y), f2bf(v.z), f2bf(v.w) };
  } else {
    o = ushort4{ 0, 0, 0, 0 };
  }
  ((ushort4*)wb)[i] = o;
}

// ---------------------------------------------------------------- x[B,C,T] -> xb[(t*2+b), C] bf16
__global__ __launch_bounds__(256) void xpose_kernel(const float* __restrict__ x,
                                                    ushort* __restrict__ xb) {
  __shared__ float s[32][33];
  int t0 = blockIdx.x * 32, k0 = blockIdx.y * 32, b = blockIdx.z;
  int tx = threadIdx.x & 31, ty = threadIdx.x >> 5;
#pragma unroll
  for (int l = 0; l < 4; ++l) {
    int k = k0 + ty + l * 8;
    s[ty + l * 8][tx] = x[((size_t)b * INCH + k) * T_ + t0 + tx];
  }
  __syncthreads();
#pragma unroll
  for (int l = 0; l < 4; ++l) {
    int t = t0 + ty + l * 8;
    xb[((size_t)(t * 2 + b)) * INCH + k0 + tx] = f2bf(s[tx][ty + l * 8]);
  }
}

// ---------------------------------------------------------------- V transpose per layer
// heads V section (t,b,n,d) -> vtg[((b*8+n)*64+d)][t]
__global__ __launch_bounds__(256) void vtrans_kernel(const ushort* __restrict__ heads,
                                                     ushort* __restrict__ vtg) {
  __shared__ ushort s[64][72];
  const int tid = threadIdx.x;
  int t0 = blockIdx.x * 64;
  int b = blockIdx.y & 1, n = blockIdx.y >> 1;
  for (int e = tid; e < 512; e += 256) {
    int r = e >> 3, c = e & 7;
    *(uint4*)&s[r][c * 8] =
        *(const uint4*)&heads[(size_t)((t0 + r) * 2 + b) * 1536 + 1024 + n * 64 + c * 8];
  }
  __syncthreads();
  for (int e = tid; e < 512; e += 256) {
    int d = e >> 3, c = e & 7;
    ushort tmp[8];
#pragma unroll
    for (int j = 0; j < 8; ++j) tmp[j] = s[c * 8 + j][d];
    *(uint4*)&vtg[((size_t)((b * 8 + n) * 64 + d)) * (size_t)T_ + t0 + c * 8] = *(uint4*)tmp;
  }
}

// ---------------------------------------------------------------- bf16 MFMA GEMM (BK=64)
template<int TM, int OUTMODE, bool RELU>
__global__ __launch_bounds__(256) void gemm_bf16(
    const ushort* __restrict__ A, const ushort* __restrict__ W,
    const float* __restrict__ bias, float* __restrict__ Cf, ushort* __restrict__ Cb,
    int M, int N, int K)
{
  __shared__ __attribute__((aligned(16))) ushort As[TM * 64];
  __shared__ __attribute__((aligned(16))) ushort Bs[128 * 64];
  const int NI = TM / 32;
  const int tid  = threadIdx.x;
  const int wave = tid >> 6, lane = tid & 63;
  const int quad = lane >> 4, lidx = lane & 15;
  const int m0 = blockIdx.y * TM, n0 = blockIdx.x * 128;
  const int r8 = lane >> 3;
  const int cs = ((lane & 7) ^ (r8 & 7)) * 8;

  float4v acc[NI * 4];
#pragma unroll
  for (int i = 0; i < NI * 4; ++i) acc[i] = (float4v){0.f, 0.f, 0.f, 0.f};

  const int wm = (wave >> 1) * (TM / 2), wn = (wave & 1) * 64;

  for (int k0 = 0; k0 < K; k0 += 64) {
    __syncthreads();
#pragma unroll
    for (int g = 0; g < TM / 32; ++g) {
      int r0 = wave * 8 + g * 32;
      gload16(A + (size_t)(m0 + r0 + r8) * K + k0 + cs, &As[r0 * 64]);
    }
#pragma unroll
    for (int g = 0; g < 4; ++g) {
      int r0 = wave * 8 + g * 32;
      gload16(W + (size_t)(n0 + r0 + r8) * K + k0 + cs, &Bs[r0 * 64]);
    }
    __syncthreads();

#pragma unroll
    for (int kb = 0; kb < 2; ++kb) {
      short8 af[NI], bf4[4];
      const int ch = (((kb * 4 + quad) ^ (lidx & 7)) * 8);
#pragma unroll
      for (int i = 0; i < NI; ++i)
        af[i] = *(const short8*)&As[(wm + i * 16 + lidx) * 64 + ch];
#pragma unroll
      for (int j = 0; j < 4; ++j)
        bf4[j] = *(const short8*)&Bs[(wn + j * 16 + lidx) * 64 + ch];
#pragma unroll
      for (int i = 0; i < NI; ++i)
#pragma unroll
        for (int j = 0; j < 4; ++j)
          acc[i * 4 + j] = __builtin_amdgcn_mfma_f32_16x16x32_bf16(af[i], bf4[j], acc[i * 4 + j], 0, 0, 0);
    }
  }

  float bj[4];
#pragma unroll
  for (int j = 0; j < 4; ++j) bj[j] = bias ? bias[n0 + wn + j * 16 + lidx] : 0.f;
#pragma unroll
  for (int i = 0; i < NI; ++i) {
    int rbase = m0 + wm + i * 16 + quad * 4;
#pragma unroll
    for (int j = 0; j < 4; ++j) {
      int col = n0 + wn + j * 16 + lidx;
#pragma unroll
      for (int reg = 0; reg < 4; ++reg) {
        float v = acc[i * 4 + j][reg] + bj[j];
        if (RELU) v = fmaxf(v, 0.f);
        size_t off = (size_t)(rbase + reg) * N + col;
        if (OUTMODE != 1) Cf[off] = v;
        if (OUTMODE != 0) Cb[off] = f2bf(v);
      }
    }
  }
}

// ---------------------------------------------------------------- MFMA flash rel-attn (swapped, split-K)
// Grid 1536 blocks; flat id F remapped XCD-exact-fit: XCD g = F%8 gets the 96
// blocks (32 i0-tiles x 3 chunks) of bn = round*8+g, so the per-bn ~1 MB
// K/V/rk working set is resident in that XCD's private 4 MB L2 for all
// staging re-reads. Block: 64 q-rows of one (b,n); wave owns q-row strip.
// AC swapped: S^T = mfma(K, Q) -> thread holds S[key][row=lidx] lane-local.
// rel_shift gather from Gbt; sel fast paths; no-max base-2 softmax in regs;
// P packed via v_cvt_pk_bf16_f32 + permlane{32,16}_swap; PV before B2.
// O/li chunk partials go to disjoint per-chunk buffers (plain stores).
#define GT 68

__device__ inline short8 bfrag(const char* base, int lidx, int quad, int kb) {
  return *(const short8*)(base + lidx * 128 + ((((kb << 2) + quad) ^ (lidx & 7)) << 4));
}

__global__ __launch_bounds__(256, 3) void attn_mfma_kernel(
    const ushort* __restrict__ heads, const ushort* __restrict__ rk,
    const ushort* __restrict__ vtg,
    const float* __restrict__ rwb, const float* __restrict__ rrb,
    float* __restrict__ O0, float* __restrict__ O1, float* __restrict__ O2,
    float* __restrict__ Lp)
{
  __shared__ __attribute__((aligned(16))) ushort Ks[64 * 64];    // swizzled [key][d]
  __shared__ __attribute__((aligned(16))) ushort Vt[64 * 64];    // swizzled [d][key]
  __shared__ __attribute__((aligned(16))) ushort Re[128 * 64];   // swizzled [w][d]
  __shared__ __attribute__((aligned(16))) ushort Gbt[128 * GT];  // [w][grow]

  const int tid  = threadIdx.x;
  // ---- XCD-exact-fit remap (assumes XCD = flat%8 round-robin dispatch).
  // F in [0,1536): g = XCD, k = slot-in-XCD (0..191), round r = k/96,
  // bn = r*8+g (each XCD owns one bn per round), kk%96 -> (i0 tile, chunk).
  {
  }
  const int F = blockIdx.x + ((blockIdx.y + (blockIdx.z << 4)) << 5);  // x + 32y + 512z
  const int g  = F & 7;
  const int k  = F >> 3;          // 0..191
  const int r  = k / 96;          // round 0/1
  const int kk = k - r * 96;      // 0..95
  const int bnl = r * 8 + g;      // logical bn
  const int i0   = (kk & 31) * 64;
  const int chunk = kk >> 5;      // 0..2
  const int b    = bnl & 1;
  const int n    = bnl >> 1;
  const int jt0 = (chunk == 0) ? 0  : (chunk == 1 ? 11 : 22);
  const int jt1 = (chunk == 0) ? 11 : (chunk == 1 ? 22 : 32);
  const int wave = tid >> 6;
  const int lane = tid & 63;
  const int quad = lane >> 4;
  const int lidx = lane & 15;
  const int r8   = lane >> 3;
  const int cs8  = ((lane & 7) ^ (r8 & 7)) * 8;
  const int bn64 = (b * 8 + n) * 64;
  const int rloc = wave * 16 + lidx;   // this thread's q-row within block

  // ---- Q fragments in registers.
  short8 qw[2], qr4[4][2], q4[2];
  {
    auto qfrag = [&](int row, int kb, const float* bias) -> short8 {
      short8 q;
      if (row < T_) q = *(const short8*)&heads[(size_t)(row * 2 + b) * 1536 + n * 64 + kb * 32 + quad * 8];
      else { for (int t = 0; t < 8; ++t) ((ushort*)&q)[t] = 0; }
      short8 o;
#pragma unroll
      for (int t = 0; t < 8; ++t) {
        float f = (bf2f((ushort)((ushort*)&q)[t]) + bias[n * 64 + kb * 32 + quad * 8 + t]) * QSCALE;
        ((ushort*)&o)[t] = f2bf(f);
      }
      return o;
    };
    qw[0] = qfrag(i0 + rloc, 0, rwb);
    qw[1] = qfrag(i0 + rloc, 1, rwb);
#pragma unroll
    for (int rt = 0; rt < 4; ++rt) {
      int row = i0 + rt * 16 + lidx;
      qr4[rt][0] = qfrag(row, 0, rrb); qr4[rt][1] = qfrag(row, 1, rrb);
    }
    int row4 = i0 + 64 + lidx;
    q4[0] = qfrag(row4, 0, rrb); q4[1] = qfrag(row4, 1, rrb);
  }

  // loop-invariant gather bases: per ktile t, addr of Gbt[w(c0)][rloc]
  int a0[4];
#pragma unroll
  for (int t = 0; t < 4; ++t)
    a0[t] = (t * 16 + quad * 4 + 63 - rloc) * GT + rloc;

  float4v oacc[4];
  float4v liacc = (float4v){0.f, 0.f, 0.f, 0.f};
#pragma unroll
  for (int dt = 0; dt < 4; ++dt) oacc[dt] = (float4v){0.f, 0.f, 0.f, 0.f};
  short8 ones8;
#pragma unroll
  for (int t = 0; t < 8; ++t) ((ushort*)&ones8)[t] = 0x3F80;   // bf16 1.0

  auto stageKRe = [&](int jt) {
    int j0 = jt * 64, qmin = j0 + 1984 - i0;
#pragma unroll
    for (int half = 0; half < 2; ++half) {
      int r0 = 8 * wave + 32 * half;
      gload16(heads + (size_t)((j0 + r0 + r8) * 2 + b) * 1536 + 512 + n * 64 + cs8, &Ks[r0 * 64]);
    }
#pragma unroll
    for (int q4i = 0; q4i < 4; ++q4i) {
      int r0 = 8 * wave + 32 * q4i;
      int qh = qmin + r0 + r8;
      int p  = (qh > T_) ? (qh - T_ - 1) : ((qh == T_) ? 0 : qh);
      gload16(rk + (size_t)p * 2048 + n * 64 + cs8, &Re[r0 * 64]);
    }
  };
  auto stageV = [&](int jt) {
    int j0 = jt * 64;
#pragma unroll
    for (int half = 0; half < 2; ++half) {
      int r0 = 8 * wave + 32 * half;
      gload16(vtg + (size_t)(bn64 + r0 + r8) * (size_t)T_ + j0 + cs8, &Vt[r0 * 64]);
    }
  };
  auto fixup = [&](int jt) {   // zero Rext[T] row (after DMA drained)
    int qmin = jt * 64 + 1984 - i0;
    int Tidx = T_ - qmin;
    if (Tidx >= 0 && Tidx < 128) {
      if (tid < 32) ((uint*)Re)[Tidx * 32 + tid] = 0u;
      __syncthreads();   // orders the write before next iter's G reads of Re
    }
  };

  stageKRe(jt0);
  stageV(jt0);
  __syncthreads();
  fixup(jt0);

  for (int jt = jt0; jt < jt1; ++jt) {
    const int qmin = jt * 64 + 1984 - i0;
    const int wth  = T_ - qmin;   // sel = (w > wth)

    // ---- AC swapped: sv[t][reg] = S[key t*16+quad*4+reg][row lidx(=rloc)]
    float4v sv[4];
#pragma unroll
    for (int t = 0; t < 4; ++t) {
      const char* KsT = (const char*)Ks + t * 2048;
      short8 kf0 = bfrag(KsT, lidx, quad, 0);
      short8 kf1 = bfrag(KsT, lidx, quad, 1);
      float4v c = {0.f, 0.f, 0.f, 0.f};
      c = __builtin_amdgcn_mfma_f32_16x16x32_bf16(kf0, qw[0], c, 0, 0, 0);
      c = __builtin_amdgcn_mfma_f32_16x16x32_bf16(kf1, qw[1], c, 0, 0, 0);
      sv[t] = c;
    }

    // ---- G: strips {wave, wave+4}; C: col->w, row->grow; aligned uint2 stores
#pragma unroll
    for (int si = 0; si < 2; ++si) {
      const int ws = wave + si * 4;
      const int w0 = ws * 16;
      const char* ReW = (const char*)Re + w0 * 128;
      short8 rb0 = bfrag(ReW, lidx, quad, 0);
      short8 rb1 = bfrag(ReW, lidx, quad, 1);
#pragma unroll
      for (int rt = 0; rt < 4; ++rt) {
        bool need = si == 0 ? (rt >= 3 - wave) : (rt <= 3 - wave);
        if (need) {
          float4v g2 = {0.f, 0.f, 0.f, 0.f};
          g2 = __builtin_amdgcn_mfma_f32_16x16x32_bf16(qr4[rt][0], rb0, g2, 0, 0, 0);
          g2 = __builtin_amdgcn_mfma_f32_16x16x32_bf16(qr4[rt][1], rb1, g2, 0, 0, 0);
          uint2 st; st.x = pkbf(g2[0], g2[1]); st.y = pkbf(g2[2], g2[3]);
          *(uint2*)&Gbt[(w0 + lidx) * GT + rt * 16 + quad * 4] = st;
        }
      }
      if (si == 0 && wth < 63) {   // grow=64 row (for sel at r=63), strips w<64
        float4v g2 = {0.f, 0.f, 0.f, 0.f};
        g2 = __builtin_amdgcn_mfma_f32_16x16x32_bf16(q4[0], rb0, g2, 0, 0, 0);
        g2 = __builtin_amdgcn_mfma_f32_16x16x32_bf16(q4[1], rb1, g2, 0, 0, 0);
        if (quad == 0) Gbt[(w0 + lidx) * GT + 64] = f2bf(g2[0]);
      }
    }
    __syncthreads();   // B1: Gbt ready; Ks/Re consumed; Vt(jt) DMA drained

    if (jt + 1 < jt1) stageKRe(jt + 1);   // DMA overlaps gather+pack+PV; drains at B2

    // ---- gather BD + no-max base-2 softmax, in registers (raw v_exp_f32)
    // sel = (c > cth) is block-uniform-classifiable: no-sel iff wth>=126,
    // all-sel iff wth<0; mixed hits <=2 iterations per block.
    if (wth >= 126) {
#pragma unroll
      for (int t = 0; t < 4; ++t)
#pragma unroll
        for (int r2 = 0; r2 < 4; ++r2)
          sv[t][r2] = __builtin_amdgcn_exp2f(sv[t][r2] + bf2f(Gbt[a0[t] + r2 * GT]));
    } else if (wth < 0) {
#pragma unroll
      for (int t = 0; t < 4; ++t)
#pragma unroll
        for (int r2 = 0; r2 < 4; ++r2)
          sv[t][r2] = __builtin_amdgcn_exp2f(sv[t][r2] + bf2f(Gbt[a0[t] + r2 * GT + 1]));
    } else {
      const int cth = wth + rloc - 63;   // sel = (c > cth)
#pragma unroll
      for (int t = 0; t < 4; ++t) {
        const int c0 = t * 16 + quad * 4;
#pragma unroll
        for (int r2 = 0; r2 < 4; ++r2) {
          int ga = a0[t] + r2 * GT + ((c0 + r2 > cth) ? 1 : 0);
          sv[t][r2] = __builtin_amdgcn_exp2f(sv[t][r2] + bf2f(Gbt[ga]));
        }
      }
    }

    // ---- V fragments (B-operand: V[key][d], d = dt*16+lidx)
    short8 vb[4][2];
#pragma unroll
    for (int dt = 0; dt < 4; ++dt) {
      const char* VtT = (const char*)Vt + dt * 2048;
      vb[dt][0] = bfrag(VtT, lidx, quad, 0);
      vb[dt][1] = bfrag(VtT, lidx, quad, 1);
    }

    // ---- pack P to bf16 + in-register quad redistribution -> PV A-frags
    // af[kb] elem j = P[row=lidx][key kb*32+quad*8+j]
    short8 af[2];
#pragma unroll
    for (int kb = 0; kb < 2; ++kb) {
      uint mm[4];
#pragma unroll
      for (int i = 0; i < 2; ++i) {
        uint e, o;
        asm("v_cvt_pk_bf16_f32 %0, %1, %2" : "=v"(e) : "v"(sv[2 * kb][2 * i]),     "v"(sv[2 * kb][2 * i + 1]));
        asm("v_cvt_pk_bf16_f32 %0, %1, %2" : "=v"(o) : "v"(sv[2 * kb + 1][2 * i]), "v"(sv[2 * kb + 1][2 * i + 1]));
        asm("v_permlane32_swap_b32 %0, %1" : "+v"(e), "+v"(o));
        asm("v_permlane16_swap_b32 %0, %1" : "+v"(e), "+v"(o));
        mm[i] = e; mm[2 + i] = o;
      }
      union { uint u[4]; short8 s; } cv;
      cv.u[0] = mm[0]; cv.u[1] = mm[1]; cv.u[2] = mm[2]; cv.u[3] = mm[3];
      af[kb] = cv.s;
    }

    // ---- PV + li (pure registers, no LDS): before B2 to extend KRe shadow
#pragma unroll
    for (int dt = 0; dt < 4; ++dt) {
      oacc[dt] = __builtin_amdgcn_mfma_f32_16x16x32_bf16(af[0], vb[dt][0], oacc[dt], 0, 0, 0);
      oacc[dt] = __builtin_amdgcn_mfma_f32_16x16x32_bf16(af[1], vb[dt][1], oacc[dt], 0, 0, 0);
    }
    liacc = __builtin_amdgcn_mfma_f32_16x16x32_bf16(af[0], ones8, liacc, 0, 0, 0);
    liacc = __builtin_amdgcn_mfma_f32_16x16x32_bf16(af[1], ones8, liacc, 0, 0, 0);

    __syncthreads();   // B2: Gbt/Vt consumed; KRe(jt+1) DMA drained

    if (jt + 1 < jt1) {
      stageV(jt + 1);   // DMA overlaps next AC/G; drains at next B1
      fixup(jt + 1);
    }
  }

  // ---- epilogue: plain stores to this chunk's disjoint partial buffer
  float* __restrict__ Oc = (chunk == 0) ? O0 : (chunk == 1 ? O1 : O2);
  float* __restrict__ Lc = Lp + chunk * (16 * T_);
  const int rowg0 = (b * 8 + n) * T_ + i0 + wave * 16 + quad * 4;
#pragma unroll
  for (int reg = 0; reg < 4; ++reg) {
    int rowg = rowg0 + reg;
#pragma unroll
    for (int dt = 0; dt < 4; ++dt)
      Oc[(size_t)rowg * 64 + dt * 16 + lidx] = oacc[dt][reg];
    if (lidx == 0) Lc[rowg] = liacc[reg];
  }
}

// ---------------------------------------------------------------- sum partials, normalize -> avec bf16
__global__ __launch_bounds__(256) void attn_norm_kernel(
    const float* __restrict__ O0, const float* __restrict__ O1,
    const float* __restrict__ O2, const float* __restrict__ Lp,
    ushort* __restrict__ avec)
{
  int idx = blockIdx.x * 256 + threadIdx.x;   // over [bn][row][d4], 16*2048*16
  int d4  = idx & 15;
  int row = (idx >> 4) & 2047;
  int bn  = idx >> 15;
  float4 v0 = ((const float4*)O0)[idx];
  float4 v1 = ((const float4*)O1)[idx];
  float4 v2 = ((const float4*)O2)[idx];
  int rg = (bn << 11) + row;
  float li = Lp[rg] + Lp[rg + 16 * T_] + Lp[rg + 32 * T_];
  float inv = 1.0f / li;
  int b = bn >> 3, n = bn & 7;
  ushort4 w = { f2bf((v0.x + v1.x + v2.x) * inv), f2bf((v0.y + v1.y + v2.y) * inv),
                f2bf((v0.z + v1.z + v2.z) * inv), f2bf((v0.w + v1.w + v2.w) * inv) };
  *(ushort4*)&avec[(size_t)(row * 2 + b) * DM + n * 64 + d4 * 4] = w;
}

// ---------------------------------------------------------------- LN(residual), dual out
__global__ __launch_bounds__(256) void ln_res_kernel(
    float* __restrict__ h, ushort* __restrict__ hb, const float* __restrict__ delta,
    const float* __restrict__ s, const float* __restrict__ bb)
{
  const int m = blockIdx.x;
  const int tid = threadIdx.x;
  float* hp = h + (size_t)m * DM;
  ushort* hbp = hb + (size_t)m * DM;
  const float* dp = delta + (size_t)m * DM;
  float x0 = hp[tid] + dp[tid];
  float x1 = hp[tid + 256] + dp[tid + 256];
  float sum = x0 + x1, sq = x0 * x0 + x1 * x1;
#pragma unroll
  for (int o = 32; o > 0; o >>= 1) { sum += __shfl_down(sum, o); sq += __shfl_down(sq, o); }
  __shared__ float part[8];
  int wv = tid >> 6;
  if ((tid & 63) == 0) { part[wv * 2] = sum; part[wv * 2 + 1] = sq; }
  __syncthreads();
  float ts = part[0] + part[2] + part[4] + part[6];
  float tq = part[1] + part[3] + part[5] + part[7];
  float mu = ts * (1.f / DM);
  float var = tq * (1.f / DM) - mu * mu;
  float rs = rsqrtf(var + 1e-5f);
  float y0 = (x0 - mu) * rs * s[tid]       + bb[tid];
  float y1 = (x1 - mu) * rs * s[tid + 256] + bb[tid + 256];
  hp[tid] = y0;       hbp[tid] = f2bf(y0);
  hp[tid + 256] = y1; hbp[tid + 256] = f2bf(y1);
}

// ---------------------------------------------------------------- classifier reorder (+bias)
__global__ __launch_bounds__(256) void reorder_kernel(const float* __restrict__ ct,
                                                      const float* __restrict__ cb,
                                                      float* __restrict__ out) {
  int idx = blockIdx.x * 256 + threadIdx.x;
  if (idx >= B_ * NCLS * T_) return;
  int t  = idx & (T_ - 1);
  int nc = (idx >> 11) & 63;
  int bb = idx >> 17;
  out[idx] = ct[(size_t)(t * B_ + bb) * 128 + nc] + cb[nc];
}

// ---------------------------------------------------------------- launch
extern "C" void kernel_launch(void* const* d_in, const int* in_sizes, int n_in,
                              void* d_out, int out_size, void* d_ws, size_t ws_size,
                              hipStream_t stream)
{
  const float* x     = (const float*)d_in[0];
  const float* emb_w = (const float*)d_in[1];
  const float* emb_b = (const float*)d_in[2];
  const float* rwb   = (const float*)d_in[3];
  const float* rrb   = (const float*)d_in[4];
  const float* qkv_w = (const float*)d_in[5];
  const float* qkv_b = (const float*)d_in[6];
  const float* rproj = (const float*)d_in[7];
  const float* o_w   = (const float*)d_in[8];
  const float* ln1s  = (const float*)d_in[9];
  const float* ln1b  = (const float*)d_in[10];
  const float* ff1w  = (const float*)d_in[11];
  const float* ff1b  = (const float*)d_in[12];
  const float* ff2w  = (const float*)d_in[13];
  const float* ff2b  = (const float*)d_in[14];
  const float* ln2s  = (const float*)d_in[15];
  const float* ln2b  = (const float*)d_in[16];
  const float* clsw  = (const float*)d_in[17];
  const float* clsb  = (const float*)d_in[18];
  float* out = (float*)d_out;

  char* p = (char*)d_ws;
  float*  h       = (float*)p;   p += (size_t)MT * DM * 4;
  float*  tmpf    = (float*)p;   p += (size_t)MT * DM * 4;
  ushort* hb      = (ushort*)p;  p += (size_t)MT * DM * 2;
  ushort* headsb  = (ushort*)p;  p += (size_t)MT * 1536 * 2;
  ushort* peb     = (ushort*)p;  p += (size_t)T_ * DM * 2;
  ushort* rk_all  = (ushort*)p;  p += (size_t)T_ * 2048 * 2;
  ushort* avecb   = (ushort*)p;  p += (size_t)MT * DM * 2;
  ushort* xfb     = (ushort*)p;  p += (size_t)MT * INCH * 2;
  ushort* emb_wb  = (ushort*)p;  p += (size_t)DM * INCH * 2;
  ushort* qkv_wb  = (ushort*)p;  p += (size_t)4 * 1536 * DM * 2;
  ushort* rproj_wb= (ushort*)p;  p += (size_t)4 * DM * DM * 2;
  ushort* o_wb    = (ushort*)p;  p += (size_t)4 * DM * DM * 2;
  ushort* ff1_wb  = (ushort*)p;  p += (size_t)4 * DI * DM * 2;
  ushort* ff2_wb  = (ushort*)p;  p += (size_t)4 * DM * DI * 2;
  float*  P2      = (float*)p;   p += (size_t)MT * DM * 4;   // chunk-2 O partial
  float*  Lp      = (float*)p;   p += (size_t)3 * 16 * T_ * 4;
  ushort* cls_wb  = (ushort*)p;  p += (size_t)128 * DM * 2;  // zero-padded bf16 clsw
  ushort* vtg     = xfb;   // region reused; live only vtrans->attn
  // chunk-0 partial = tmpf (free during attn); chunk-1 partial = xfb tail
  // (xfb is 16 MB; vtg uses only the first 4 MB; ff1 rewrites xfb later).
  float*  P0      = tmpf;
  float*  P1      = (float*)(xfb + (size_t)16 * 64 * T_);   // xfb + 4 MB

  cvt6_kernel<<<dim3(4096, 6), 256, 0, stream>>>(
      emb_w, emb_wb, DM * INCH / 4,
      qkv_w, qkv_wb, 4 * 1536 * DM / 4,
      rproj, rproj_wb, 4 * DM * DM / 4,
      o_w,   o_wb,   4 * DM * DM / 4,
      ff1w,  ff1_wb, 4 * DI * DM / 4,
      ff2w,  ff2_wb, 4 * DM * DI / 4);
  clsw_cvt_kernel<<<64, 256, 0, stream>>>(clsw, cls_wb);
  pos_kernel<<<(T_ * DM) / 256, 256, 0, stream>>>(peb);
  xpose_kernel<<<dim3(T_ / 32, INCH / 32, B_), 256, 0, stream>>>(x, xfb);

  gemm_bf16<64, 2, false><<<dim3(DM / 128, MT / 64), 256, 0, stream>>>(
      xfb, emb_wb, emb_b, h, hb, MT, DM, INCH);
  gemm_bf16<128, 1, false><<<dim3(2048 / 128, T_ / 128), 256, 0, stream>>>(
      peb, rproj_wb, nullptr, nullptr, rk_all, T_, 2048, DM);

  for (int l = 0; l < 4; ++l) {
    gemm_bf16<128, 1, false><<<dim3(1536 / 128, MT / 128), 256, 0, stream>>>(
        hb, qkv_wb + (size_t)l * 1536 * DM, qkv_b + l * 1536, nullptr, headsb, MT, 1536, DM);
    vtrans_kernel<<<dim3(T_ / 64, B_ * NH), 256, 0, stream>>>(headsb, vtg);
    attn_mfma_kernel<<<dim3(T_ / 64, B_ * NH, 3), 256, 0, stream>>>(
        headsb, rk_all + (size_t)l * 512, vtg, rwb, rrb, P0, P1, P2, Lp);
    attn_norm_kernel<<<(16 * T_ * 16) / 256, 256, 0, stream>>>(P0, P1, P2, Lp, avecb);
    gemm_bf16<32, 0, false><<<dim3(DM / 128, MT / 32), 256, 0, stream>>>(
        avecb, o_wb + (size_t)l * DM * DM, nullptr, tmpf, nullptr, MT, DM, DM);
    ln_res_kernel<<<MT, 256, 0, stream>>>(h, hb, tmpf, ln1s + l * DM, ln1b + l * DM);
    gemm_bf16<128, 1, true><<<dim3(DI / 128, MT / 128), 256, 0, stream>>>(
        hb, ff1_wb + (size_t)l * DI * DM, ff1b + l * DI, nullptr, xfb, MT, DI, DM);
    gemm_bf16<32, 0, false><<<dim3(DM / 128, MT / 32), 256, 0, stream>>>(
        xfb, ff2_wb + (size_t)l * DM * DI, ff2b + l * DM, tmpf, nullptr, MT, DM, DI);
    ln_res_kernel<<<MT, 256, 0, stream>>>(h, hb, tmpf, ln2s + l * DM, ln2b + l * DM);
  }

  // classifier: bf16 MFMA, N padded to 128 (rows 64.. are zero); bias in reorder
  gemm_bf16<32, 0, false><<<dim3(1, MT / 32), 256, 0, stream>>>(
      hb, cls_wb, nullptr, tmpf, nullptr, MT, 128, DM);
  reorder_kernel<<<(B_ * NCLS * T_) / 256, 256, 0, stream>>>(tmpf, clsb, out);
}